// Round 2
// baseline (1213.122 us; speedup 1.0000x reference)
//
#include <hip/hip_runtime.h>
#include <hip/hip_bf16.h>
#include <stdint.h>

#define NPROT 19000
#define NDRUG 4000
#define NCELL 16
#define BATCH 4096
#define NEDGE 40000
#define L0 2048
#define L1DIM 1024
#define INDIM 38032
#define HALFDIM 19016

typedef float f32x4 __attribute__((ext_vector_type(4)));
typedef short s16x8 __attribute__((ext_vector_type(8)));

__global__ void zero_int_kernel(int* __restrict__ p, int n) {
    int i = blockIdx.x * 256 + threadIdx.x;
    if (i < n) p[i] = 0;
}

__global__ void hist_kernel(const int* __restrict__ prot, int* __restrict__ hist) {
    int e = blockIdx.x * 256 + threadIdx.x;
    if (e < NEDGE) atomicAdd(&hist[prot[e]], 1);
}

__global__ __launch_bounds__(256) void scan_kernel(const int* __restrict__ hist, int* __restrict__ row_ptr) {
    __shared__ int part[256];
    int t = threadIdx.x;
    const int CH_ = (NPROT + 255) / 256;  // 75
    int s = 0;
    for (int j = 0; j < CH_; ++j) {
        int idx = t * CH_ + j;
        if (idx < NPROT) s += hist[idx];
    }
    part[t] = s;
    __syncthreads();
    if (t == 0) {
        int run = 0;
        for (int i = 0; i < 256; ++i) { int v = part[i]; part[i] = run; run += v; }
    }
    __syncthreads();
    int run = part[t];
    for (int j = 0; j < CH_; ++j) {
        int idx = t * CH_ + j;
        if (idx < NPROT) { row_ptr[idx] = run; run += hist[idx]; }
    }
    if (t == 255) row_ptr[NPROT] = NEDGE;
}

__global__ void scatter_kernel(const int* __restrict__ prot, const int* __restrict__ drug,
                               const int* __restrict__ row_ptr, int* __restrict__ cnt,
                               int* __restrict__ col, int* __restrict__ psrt) {
    int e = blockIdx.x * 256 + threadIdx.x;
    if (e < NEDGE) {
        int p = prot[e];
        int pos = row_ptr[p] + atomicAdd(&cnt[p], 1);
        col[pos] = drug[e];
        psrt[pos] = p;
    }
}

// reference uses .set(1.0): duplicate (drug,prot) edges count once -> mark dups -1
__global__ void dedup_kernel(const int* __restrict__ row_ptr, int* __restrict__ col) {
    int p = blockIdx.x * 256 + threadIdx.x;
    if (p < NPROT) {
        int beg = row_ptr[p], end = row_ptr[p + 1];
        for (int i = beg + 1; i < end; ++i) {
            int d = col[i];
            for (int j = beg; j < i; ++j)
                if (col[j] == d) { col[i] = -1; break; }
        }
    }
}

// BASE[c][ch] = b0[ch] + W0[ch, 19000+c] + W0[ch, 38016+c]
__global__ void base_kernel(const float* __restrict__ W0, const float* __restrict__ b0,
                            float* __restrict__ BASE) {
    int i = blockIdx.x * 256 + threadIdx.x;
    if (i < NCELL * L0) {
        int c = i >> 11, ch = i & 2047;
        const float* wr = W0 + (size_t)ch * INDIM;
        BASE[(size_t)c * L0 + ch] = b0[ch] + wr[NPROT + c] + wr[HALFDIM + NPROT + c];
    }
}

// Edge-parallel SpMM: SA[d][ch] = sum_{p in drug d} W0[ch][p] (half A),
// SB same over columns 19016+p (half B). Block owns CH channels of one half.
// Per protein-chunk: stage W0 rows to LDS (coalesced), then lane-parallel
// over the chunk's (pre-sorted) edge range with LDS atomic accumulate.
#define CH 2
#define CHUNK 2048
__global__ __launch_bounds__(256) void drug_sum_kernel(const float* __restrict__ W0,
                                                       const int* __restrict__ row_ptr,
                                                       const int* __restrict__ col,
                                                       const int* __restrict__ psrt,
                                                       float* __restrict__ SA,
                                                       float* __restrict__ SB) {
    __shared__ float acc[CH][NDRUG];   // 32000 B
    __shared__ float wst[CH][CHUNK];   // 16384 B -> total 48384 B, 3 blocks/CU
    int t = threadIdx.x;
    int hb = blockIdx.y;
    int ch0 = blockIdx.x * CH;
    for (int i = t; i < CH * NDRUG; i += 256) ((float*)acc)[i] = 0.f;
    __syncthreads();
    size_t colbase = (size_t)hb * HALFDIM;
    for (int p0 = 0; p0 < NPROT; p0 += CHUNK) {
        int pc = min(CHUNK, NPROT - p0);
#pragma unroll
        for (int c = 0; c < CH; ++c) {
            const float* src = W0 + (size_t)(ch0 + c) * INDIM + colbase + p0;
            for (int i = t * 4; i < pc; i += 1024)
                *(float4*)&wst[c][i] = *(const float4*)(src + i);
        }
        __syncthreads();
        int ebeg = row_ptr[p0];
        int eend = row_ptr[p0 + pc];
        for (int e = ebeg + t; e < eend; e += 256) {
            int d = col[e];
            int p = psrt[e] - p0;
            if (d >= 0) {
#pragma unroll
                for (int c = 0; c < CH; ++c)
                    atomicAdd(&acc[c][d], wst[c][p]);
            }
        }
        __syncthreads();
    }
    float* dst = hb ? SB : SA;
    for (int d = t; d < NDRUG; d += 256) {
        float2 v;
        v.x = acc[0][d]; v.y = acc[1][d];
        *(float2*)(dst + (size_t)d * L0 + ch0) = v;
    }
}

__global__ void cvtw1_kernel(const float* __restrict__ W1, __hip_bfloat16* __restrict__ W1b) {
    int i = blockIdx.x * 256 + threadIdx.x;  // one float4 each
    const int n = L1DIM * L0 / 4;
    if (i < n) {
        float4 v = ((const float4*)W1)[i];
        union { ushort4 u; __hip_bfloat16 h[4]; } pk;
        pk.h[0] = __float2bfloat16(v.x);
        pk.h[1] = __float2bfloat16(v.y);
        pk.h[2] = __float2bfloat16(v.z);
        pk.h[3] = __float2bfloat16(v.w);
        ((ushort4*)W1b)[i] = pk.u;
    }
}

// h1[b]        = relu(BASE[c] + SA[d1] + SB[d2])  (x1)
// h1[4096+b]   = relu(BASE[c] + SA[d2] + SB[d1])  (x2)
__global__ __launch_bounds__(256) void build_h_kernel(const int* __restrict__ dp,
                                                      const int* __restrict__ cl,
                                                      const float* __restrict__ SA,
                                                      const float* __restrict__ SB,
                                                      const float* __restrict__ BASE,
                                                      __hip_bfloat16* __restrict__ h1) {
    int b = blockIdx.x;
    int d1 = dp[2 * b], d2 = dp[2 * b + 1], c = cl[b];
    const float* bs = BASE + (size_t)c * L0;
    const float* a1 = SA + (size_t)d1 * L0;
    const float* a2 = SA + (size_t)d2 * L0;
    const float* s1 = SB + (size_t)d1 * L0;
    const float* s2 = SB + (size_t)d2 * L0;
    for (int ch = threadIdx.x * 4; ch < L0; ch += 1024) {
        float4 vb = *(const float4*)(bs + ch);
        float4 va1 = *(const float4*)(a1 + ch);
        float4 va2 = *(const float4*)(a2 + ch);
        float4 vs1 = *(const float4*)(s1 + ch);
        float4 vs2 = *(const float4*)(s2 + ch);
        union { ushort4 u; __hip_bfloat16 h[4]; } p1, p2;
        const float* fb = (const float*)&vb;
        const float* fa1 = (const float*)&va1;
        const float* fa2 = (const float*)&va2;
        const float* fs1 = (const float*)&vs1;
        const float* fs2 = (const float*)&vs2;
#pragma unroll
        for (int j = 0; j < 4; ++j) {
            float z1 = fb[j] + fa1[j] + fs2[j];
            float z2 = fb[j] + fa2[j] + fs1[j];
            p1.h[j] = __float2bfloat16(fmaxf(z1, 0.f));
            p2.h[j] = __float2bfloat16(fmaxf(z2, 0.f));
        }
        *(ushort4*)((__hip_bfloat16*)h1 + (size_t)b * L0 + ch) = p1.u;
        *(ushort4*)((__hip_bfloat16*)h1 + (size_t)(BATCH + b) * L0 + ch) = p2.u;
    }
}

// C = relu(A @ B^T + bias), A: MxK bf16, B: NxK bf16 (W1), C: MxN bf16
#define BM 128
#define BN 128
#define BKK 32
__global__ __launch_bounds__(256) void gemm_kernel(const __hip_bfloat16* __restrict__ A,
                                                   const __hip_bfloat16* __restrict__ B,
                                                   const float* __restrict__ bias,
                                                   __hip_bfloat16* __restrict__ C,
                                                   int M, int N, int K) {
    __shared__ __hip_bfloat16 As[BM * BKK];
    __shared__ __hip_bfloat16 Bs[BN * BKK];
    int t = threadIdx.x;
    int ntiles = N / BN;
    int bx = blockIdx.x % ntiles;
    int by = blockIdx.x / ntiles;
    int brow = by * BM, bcol = bx * BN;
    int w = t >> 6, l = t & 63;
    int wr = w >> 1, wc = w & 1;
    f32x4 acc[4][4] = {};
    int row = l & 15, ko = (l >> 4) * 8;
    for (int k0 = 0; k0 < K; k0 += BKK) {
#pragma unroll
        for (int i = 0; i < 2; ++i) {
            int idx = i * 256 + t;
            int r = idx >> 2, cb = (idx & 3) * 8;
            __builtin_amdgcn_global_load_lds(
                (const __attribute__((address_space(1))) void*)(A + (size_t)(brow + r) * K + k0 + cb),
                (__attribute__((address_space(3))) void*)(&As[idx * 8]), 16, 0, 0);
            __builtin_amdgcn_global_load_lds(
                (const __attribute__((address_space(1))) void*)(B + (size_t)(bcol + r) * K + k0 + cb),
                (__attribute__((address_space(3))) void*)(&Bs[idx * 8]), 16, 0, 0);
        }
        __syncthreads();
        s16x8 af[4], bfr[4];
#pragma unroll
        for (int m = 0; m < 4; ++m)
            af[m] = *(const s16x8*)(&As[(wr * 64 + m * 16 + row) * BKK + ko]);
#pragma unroll
        for (int n = 0; n < 4; ++n)
            bfr[n] = *(const s16x8*)(&Bs[(wc * 64 + n * 16 + row) * BKK + ko]);
#pragma unroll
        for (int m = 0; m < 4; ++m)
#pragma unroll
            for (int n = 0; n < 4; ++n)
                acc[m][n] = __builtin_amdgcn_mfma_f32_16x16x32_bf16(af[m], bfr[n], acc[m][n], 0, 0, 0);
        __syncthreads();
    }
    int cr = (l >> 4) * 4;
    int cc = l & 15;
#pragma unroll
    for (int m = 0; m < 4; ++m)
#pragma unroll
        for (int n = 0; n < 4; ++n) {
#pragma unroll
            for (int j = 0; j < 4; ++j) {
                int grow = brow + wr * 64 + m * 16 + cr + j;
                int gcol = bcol + wc * 64 + n * 16 + cc;
                float v = acc[m][n][j] + bias[gcol];
                C[(size_t)grow * N + gcol] = __float2bfloat16(fmaxf(v, 0.f));
            }
        }
}

// out[r] = b2 + sum_o h2[r][o] * W2[o]
__global__ __launch_bounds__(128) void out_kernel(const __hip_bfloat16* __restrict__ h2,
                                                  const float* __restrict__ W2,
                                                  const float* __restrict__ b2,
                                                  float* __restrict__ out) {
    int r = blockIdx.x;
    int t = threadIdx.x;
    union { uint4 u; __hip_bfloat16 h[8]; } pk;
    pk.u = *(const uint4*)(h2 + (size_t)r * L1DIM + t * 8);
    float s = 0.f;
#pragma unroll
    for (int j = 0; j < 8; ++j) s += __bfloat162float(pk.h[j]) * W2[t * 8 + j];
    for (int o = 32; o > 0; o >>= 1) s += __shfl_down(s, o);
    __shared__ float red[2];
    if ((t & 63) == 0) red[t >> 6] = s;
    __syncthreads();
    if (t == 0) out[r] = red[0] + red[1] + b2[0];
}

extern "C" void kernel_launch(void* const* d_in, const int* in_sizes, int n_in,
                              void* d_out, int out_size, void* d_ws, size_t ws_size,
                              hipStream_t stream) {
    const int* drug_pairs = (const int*)d_in[0];
    const int* cell_lines = (const int*)d_in[1];
    const int* dpi_drug = (const int*)d_in[2];
    const int* dpi_prot = (const int*)d_in[3];
    const float* W0 = (const float*)d_in[4];
    const float* b0 = (const float*)d_in[5];
    const float* W1 = (const float*)d_in[6];
    const float* b1 = (const float*)d_in[7];
    const float* W2 = (const float*)d_in[8];
    const float* b2 = (const float*)d_in[9];
    float* out = (float*)d_out;

    char* ws = (char*)d_ws;
    size_t off = 0;
    auto alloc = [&](size_t bytes) {
        char* p = ws + off;
        off += (bytes + 255) & ~(size_t)255;
        return p;
    };
    float* SA = (float*)alloc((size_t)NDRUG * L0 * 4);
    float* SB = (float*)alloc((size_t)NDRUG * L0 * 4);
    float* BASE = (float*)alloc((size_t)NCELL * L0 * 4);
    __hip_bfloat16* W1b = (__hip_bfloat16*)alloc((size_t)L1DIM * L0 * 2);
    __hip_bfloat16* h1 = (__hip_bfloat16*)alloc((size_t)2 * BATCH * L0 * 2);
    __hip_bfloat16* h2 = (__hip_bfloat16*)alloc((size_t)2 * BATCH * L1DIM * 2);
    int* hist = (int*)alloc((size_t)NPROT * 4);
    int* cnt = (int*)alloc((size_t)NPROT * 4);
    int* row_ptr = (int*)alloc((size_t)(NPROT + 1) * 4);
    int* col = (int*)alloc((size_t)NEDGE * 4);
    int* psrt = (int*)alloc((size_t)NEDGE * 4);

    zero_int_kernel<<<(NPROT + 255) / 256, 256, 0, stream>>>(hist, NPROT);
    zero_int_kernel<<<(NPROT + 255) / 256, 256, 0, stream>>>(cnt, NPROT);
    hist_kernel<<<(NEDGE + 255) / 256, 256, 0, stream>>>(dpi_prot, hist);
    scan_kernel<<<1, 256, 0, stream>>>(hist, row_ptr);
    scatter_kernel<<<(NEDGE + 255) / 256, 256, 0, stream>>>(dpi_prot, dpi_drug, row_ptr, cnt, col, psrt);
    dedup_kernel<<<(NPROT + 255) / 256, 256, 0, stream>>>(row_ptr, col);
    base_kernel<<<(NCELL * L0 + 255) / 256, 256, 0, stream>>>(W0, b0, BASE);
    drug_sum_kernel<<<dim3(L0 / CH, 2), 256, 0, stream>>>(W0, row_ptr, col, psrt, SA, SB);
    cvtw1_kernel<<<(L1DIM * L0 / 4 + 255) / 256, 256, 0, stream>>>(W1, W1b);
    build_h_kernel<<<BATCH, 256, 0, stream>>>(drug_pairs, cell_lines, SA, SB, BASE, h1);
    gemm_kernel<<<(2 * BATCH / BM) * (L1DIM / BN), 256, 0, stream>>>(h1, W1b, b1, h2,
                                                                     2 * BATCH, L1DIM, L0);
    out_kernel<<<2 * BATCH, 128, 0, stream>>>(h2, W2, b2, out);
}

// Round 3
// 564.612 us; speedup vs baseline: 2.1486x; 2.1486x over previous
//
#include <hip/hip_runtime.h>
#include <hip/hip_bf16.h>
#include <stdint.h>

#define NPROT 19000
#define NDRUG 4000
#define NCELL 16
#define BATCH 4096
#define NEDGE 40000
#define L0 2048
#define L1DIM 1024
#define INDIM 38032
#define HALFDIM 19016

typedef float f32x4 __attribute__((ext_vector_type(4)));
typedef short s16x8 __attribute__((ext_vector_type(8)));

__global__ void zero_int_kernel(int* __restrict__ p, int n) {
    int i = blockIdx.x * 256 + threadIdx.x;
    if (i < n) p[i] = 0;
}

__global__ void hist_kernel(const int* __restrict__ drug, int* __restrict__ hist) {
    int e = blockIdx.x * 256 + threadIdx.x;
    if (e < NEDGE) atomicAdd(&hist[drug[e]], 1);
}

// generic single-block exclusive scan: row_ptr[0..n], row_ptr[n] = total
__global__ __launch_bounds__(256) void scan_kernel(const int* __restrict__ hist,
                                                   int* __restrict__ row_ptr, int n) {
    __shared__ int part[256];
    int t = threadIdx.x;
    int per = (n + 255) / 256;
    int s = 0;
    for (int j = 0; j < per; ++j) {
        int idx = t * per + j;
        if (idx < n) s += hist[idx];
    }
    part[t] = s;
    __syncthreads();
    if (t == 0) {
        int run = 0;
        for (int i = 0; i < 256; ++i) { int v = part[i]; part[i] = run; run += v; }
    }
    __syncthreads();
    int run = part[t];
    for (int j = 0; j < per; ++j) {
        int idx = t * per + j;
        if (idx < n) { row_ptr[idx] = run; run += hist[idx]; }
    }
    if (t == 255) row_ptr[n] = run;
}

// CSR by drug: dtmp[dptr[d] + k] = protein
__global__ void scatter_kernel(const int* __restrict__ drug, const int* __restrict__ prot,
                               const int* __restrict__ dptr, int* __restrict__ cnt,
                               int* __restrict__ dtmp) {
    int e = blockIdx.x * 256 + threadIdx.x;
    if (e < NEDGE) {
        int d = drug[e];
        int pos = dptr[d] + atomicAdd(&cnt[d], 1);
        dtmp[pos] = prot[e];
    }
}

// per-drug: insertion-sort protein list, dedup (reference .set(1.0) semantics),
// emit u16 list + deduped count
__global__ void sortdedup_kernel(const int* __restrict__ dptr, int* __restrict__ dtmp,
                                 unsigned short* __restrict__ dlist, int* __restrict__ dcnt) {
    int d = blockIdx.x * 256 + threadIdx.x;
    if (d >= NDRUG) return;
    int beg = dptr[d], end = dptr[d + 1];
    for (int i = beg + 1; i < end; ++i) {
        int v = dtmp[i];
        int j = i - 1;
        while (j >= beg && dtmp[j] > v) { dtmp[j + 1] = dtmp[j]; --j; }
        dtmp[j + 1] = v;
    }
    int c = 0, prev = -1;
    for (int i = beg; i < end; ++i) {
        int v = dtmp[i];
        if (v != prev) { dlist[beg + c] = (unsigned short)v; ++c; prev = v; }
    }
    dcnt[d] = c;
}

// BASE[c][ch] = b0[ch] + W0[ch, 19000+c] + W0[ch, 38016+c]
__global__ void base_kernel(const float* __restrict__ W0, const float* __restrict__ b0,
                            float* __restrict__ BASE) {
    int i = blockIdx.x * 256 + threadIdx.x;
    if (i < NCELL * L0) {
        int c = i >> 11, ch = i & 2047;
        const float* wr = W0 + (size_t)ch * INDIM;
        BASE[(size_t)c * L0 + ch] = b0[ch] + wr[NPROT + c] + wr[HALFDIM + NPROT + c];
    }
}

// Atomic-free drug sum. Block owns CH=2 channels of one half (XCD-swizzled).
// Thread exclusively owns 16 strided drugs -> register accumulators.
// W0 chunk-staged to LDS via global_load_lds, double-buffered.
#define CH 2
#define CHUNK 2048
#define NCHUNK ((NPROT + CHUNK - 1) / CHUNK)
#define DPT 16
__global__ __launch_bounds__(256) void drug_sum_kernel(const float* __restrict__ W0,
                                                       const int* __restrict__ dptr,
                                                       const int* __restrict__ dcnt,
                                                       const unsigned short* __restrict__ dlist,
                                                       float* __restrict__ SA,
                                                       float* __restrict__ SB) {
    __shared__ float wst[2][CH][CHUNK];  // 32 KB
    int t = threadIdx.x;
    int bid = blockIdx.x;
    // XCD swizzle: blocks covering the same 64B output line group share bid%8
    int j = bid & 7, i = bid >> 3;
    int hb = (i >> 7) & 1;
    int chpair = (j << 7) + (i & 127);
    int ch0 = chpair * 2;
    size_t colbase = (size_t)hb * HALFDIM;

    int cur[DPT], end_[DPT];
    float a0[DPT], a1[DPT];
#pragma unroll
    for (int k = 0; k < DPT; ++k) {
        int d = t + (k << 8);
        bool valid = d < NDRUG;
        int b = valid ? dptr[d] : 0;
        cur[k] = b;
        end_[k] = valid ? b + dcnt[d] : 0;
        a0[k] = 0.f;
        a1[k] = 0.f;
    }

    // stage chunk (pc floats per channel) into wst[buf]
    auto stage = [&](int buf, int p0, int pc) {
#pragma unroll
        for (int c = 0; c < CH; ++c) {
            const float* src = W0 + (size_t)(ch0 + c) * INDIM + colbase + p0;
            for (int o = t; o * 4 < pc; o += 256) {
                __builtin_amdgcn_global_load_lds(
                    (const __attribute__((address_space(1))) void*)(src + o * 4),
                    (__attribute__((address_space(3))) void*)(&wst[buf][c][o * 4]), 16, 0, 0);
            }
        }
    };
    stage(0, 0, CHUNK);
    __syncthreads();

    for (int cidx = 0; cidx < NCHUNK; ++cidx) {
        int p0 = cidx * CHUNK;
        int pc = min(CHUNK, NPROT - p0);
        int plim = p0 + pc;
        int buf = cidx & 1;
        if (cidx + 1 < NCHUNK) {
            int np0 = p0 + CHUNK;
            stage(buf ^ 1, np0, min(CHUNK, NPROT - np0));
        }
        const float* w0s = wst[buf][0];
        const float* w1s = wst[buf][1];
#pragma unroll
        for (int k = 0; k < DPT; ++k) {
            int c = cur[k], e = end_[k];
            while (c < e) {
                int p = dlist[c];
                if (p >= plim) break;
                a0[k] += w0s[p - p0];
                a1[k] += w1s[p - p0];
                ++c;
            }
            cur[k] = c;
        }
        __syncthreads();  // drains staged loads (vmcnt) + protects buf reuse
    }

    float* dst = hb ? SB : SA;
#pragma unroll
    for (int k = 0; k < DPT; ++k) {
        int d = t + (k << 8);
        if (d < NDRUG) {
            float2 v;
            v.x = a0[k];
            v.y = a1[k];
            *(float2*)(dst + (size_t)d * L0 + ch0) = v;
        }
    }
}

__global__ void cvtw1_kernel(const float* __restrict__ W1, __hip_bfloat16* __restrict__ W1b) {
    int i = blockIdx.x * 256 + threadIdx.x;  // one float4 each
    const int n = L1DIM * L0 / 4;
    if (i < n) {
        float4 v = ((const float4*)W1)[i];
        union { ushort4 u; __hip_bfloat16 h[4]; } pk;
        pk.h[0] = __float2bfloat16(v.x);
        pk.h[1] = __float2bfloat16(v.y);
        pk.h[2] = __float2bfloat16(v.z);
        pk.h[3] = __float2bfloat16(v.w);
        ((ushort4*)W1b)[i] = pk.u;
    }
}

// h1[b]      = relu(BASE[c] + SA[d1] + SB[d2])  (x1)
// h1[4096+b] = relu(BASE[c] + SA[d2] + SB[d1])  (x2)
__global__ __launch_bounds__(256) void build_h_kernel(const int* __restrict__ dp,
                                                      const int* __restrict__ cl,
                                                      const float* __restrict__ SA,
                                                      const float* __restrict__ SB,
                                                      const float* __restrict__ BASE,
                                                      __hip_bfloat16* __restrict__ h1) {
    int b = blockIdx.x;
    int d1 = dp[2 * b], d2 = dp[2 * b + 1], c = cl[b];
    const float* bs = BASE + (size_t)c * L0;
    const float* a1 = SA + (size_t)d1 * L0;
    const float* a2 = SA + (size_t)d2 * L0;
    const float* s1 = SB + (size_t)d1 * L0;
    const float* s2 = SB + (size_t)d2 * L0;
    for (int ch = threadIdx.x * 4; ch < L0; ch += 1024) {
        float4 vb = *(const float4*)(bs + ch);
        float4 va1 = *(const float4*)(a1 + ch);
        float4 va2 = *(const float4*)(a2 + ch);
        float4 vs1 = *(const float4*)(s1 + ch);
        float4 vs2 = *(const float4*)(s2 + ch);
        union { ushort4 u; __hip_bfloat16 h[4]; } p1, p2;
        const float* fb = (const float*)&vb;
        const float* fa1 = (const float*)&va1;
        const float* fa2 = (const float*)&va2;
        const float* fs1 = (const float*)&vs1;
        const float* fs2 = (const float*)&vs2;
#pragma unroll
        for (int j = 0; j < 4; ++j) {
            float z1 = fb[j] + fa1[j] + fs2[j];
            float z2 = fb[j] + fa2[j] + fs1[j];
            p1.h[j] = __float2bfloat16(fmaxf(z1, 0.f));
            p2.h[j] = __float2bfloat16(fmaxf(z2, 0.f));
        }
        *(ushort4*)((__hip_bfloat16*)h1 + (size_t)b * L0 + ch) = p1.u;
        *(ushort4*)((__hip_bfloat16*)h1 + (size_t)(BATCH + b) * L0 + ch) = p2.u;
    }
}

// C = relu(A @ B^T + bias), A: MxK bf16, B: NxK bf16 (W1), C: MxN bf16
#define BM 128
#define BN 128
#define BKK 32
__global__ __launch_bounds__(256) void gemm_kernel(const __hip_bfloat16* __restrict__ A,
                                                   const __hip_bfloat16* __restrict__ B,
                                                   const float* __restrict__ bias,
                                                   __hip_bfloat16* __restrict__ C,
                                                   int M, int N, int K) {
    __shared__ __hip_bfloat16 As[BM * BKK];
    __shared__ __hip_bfloat16 Bs[BN * BKK];
    int t = threadIdx.x;
    int ntiles = N / BN;
    int bx = blockIdx.x % ntiles;
    int by = blockIdx.x / ntiles;
    int brow = by * BM, bcol = bx * BN;
    int w = t >> 6, l = t & 63;
    int wr = w >> 1, wc = w & 1;
    f32x4 acc[4][4] = {};
    int row = l & 15, ko = (l >> 4) * 8;
    for (int k0 = 0; k0 < K; k0 += BKK) {
#pragma unroll
        for (int i = 0; i < 2; ++i) {
            int idx = i * 256 + t;
            int r = idx >> 2, cb = (idx & 3) * 8;
            __builtin_amdgcn_global_load_lds(
                (const __attribute__((address_space(1))) void*)(A + (size_t)(brow + r) * K + k0 + cb),
                (__attribute__((address_space(3))) void*)(&As[idx * 8]), 16, 0, 0);
            __builtin_amdgcn_global_load_lds(
                (const __attribute__((address_space(1))) void*)(B + (size_t)(bcol + r) * K + k0 + cb),
                (__attribute__((address_space(3))) void*)(&Bs[idx * 8]), 16, 0, 0);
        }
        __syncthreads();
        s16x8 af[4], bfr[4];
#pragma unroll
        for (int m = 0; m < 4; ++m)
            af[m] = *(const s16x8*)(&As[(wr * 64 + m * 16 + row) * BKK + ko]);
#pragma unroll
        for (int n = 0; n < 4; ++n)
            bfr[n] = *(const s16x8*)(&Bs[(wc * 64 + n * 16 + row) * BKK + ko]);
#pragma unroll
        for (int m = 0; m < 4; ++m)
#pragma unroll
            for (int n = 0; n < 4; ++n)
                acc[m][n] = __builtin_amdgcn_mfma_f32_16x16x32_bf16(af[m], bfr[n], acc[m][n], 0, 0, 0);
        __syncthreads();
    }
    int cr = (l >> 4) * 4;
    int cc = l & 15;
#pragma unroll
    for (int m = 0; m < 4; ++m)
#pragma unroll
        for (int n = 0; n < 4; ++n) {
#pragma unroll
            for (int j = 0; j < 4; ++j) {
                int grow = brow + wr * 64 + m * 16 + cr + j;
                int gcol = bcol + wc * 64 + n * 16 + cc;
                float v = acc[m][n][j] + bias[gcol];
                C[(size_t)grow * N + gcol] = __float2bfloat16(fmaxf(v, 0.f));
            }
        }
}

// out[r] = b2 + sum_o h2[r][o] * W2[o]
__global__ __launch_bounds__(128) void out_kernel(const __hip_bfloat16* __restrict__ h2,
                                                  const float* __restrict__ W2,
                                                  const float* __restrict__ b2,
                                                  float* __restrict__ out) {
    int r = blockIdx.x;
    int t = threadIdx.x;
    union { uint4 u; __hip_bfloat16 h[8]; } pk;
    pk.u = *(const uint4*)(h2 + (size_t)r * L1DIM + t * 8);
    float s = 0.f;
#pragma unroll
    for (int j = 0; j < 8; ++j) s += __bfloat162float(pk.h[j]) * W2[t * 8 + j];
    for (int o = 32; o > 0; o >>= 1) s += __shfl_down(s, o);
    __shared__ float red[2];
    if ((t & 63) == 0) red[t >> 6] = s;
    __syncthreads();
    if (t == 0) out[r] = red[0] + red[1] + b2[0];
}

extern "C" void kernel_launch(void* const* d_in, const int* in_sizes, int n_in,
                              void* d_out, int out_size, void* d_ws, size_t ws_size,
                              hipStream_t stream) {
    const int* drug_pairs = (const int*)d_in[0];
    const int* cell_lines = (const int*)d_in[1];
    const int* dpi_drug = (const int*)d_in[2];
    const int* dpi_prot = (const int*)d_in[3];
    const float* W0 = (const float*)d_in[4];
    const float* b0 = (const float*)d_in[5];
    const float* W1 = (const float*)d_in[6];
    const float* b1 = (const float*)d_in[7];
    const float* W2 = (const float*)d_in[8];
    const float* b2 = (const float*)d_in[9];
    float* out = (float*)d_out;

    char* ws = (char*)d_ws;
    size_t off = 0;
    auto alloc = [&](size_t bytes) {
        char* p = ws + off;
        off += (bytes + 255) & ~(size_t)255;
        return p;
    };
    float* SA = (float*)alloc((size_t)NDRUG * L0 * 4);
    float* SB = (float*)alloc((size_t)NDRUG * L0 * 4);
    float* BASE = (float*)alloc((size_t)NCELL * L0 * 4);
    __hip_bfloat16* W1b = (__hip_bfloat16*)alloc((size_t)L1DIM * L0 * 2);
    __hip_bfloat16* h1 = (__hip_bfloat16*)alloc((size_t)2 * BATCH * L0 * 2);
    __hip_bfloat16* h2 = (__hip_bfloat16*)alloc((size_t)2 * BATCH * L1DIM * 2);
    int* hist = (int*)alloc((size_t)NDRUG * 4);
    int* cnt = (int*)alloc((size_t)NDRUG * 4);
    int* dptr = (int*)alloc((size_t)(NDRUG + 1) * 4);
    int* dtmp = (int*)alloc((size_t)NEDGE * 4);
    unsigned short* dlist = (unsigned short*)alloc((size_t)NEDGE * 2);
    int* dcnt = (int*)alloc((size_t)NDRUG * 4);

    zero_int_kernel<<<(NDRUG + 255) / 256, 256, 0, stream>>>(hist, NDRUG);
    zero_int_kernel<<<(NDRUG + 255) / 256, 256, 0, stream>>>(cnt, NDRUG);
    hist_kernel<<<(NEDGE + 255) / 256, 256, 0, stream>>>(dpi_drug, hist);
    scan_kernel<<<1, 256, 0, stream>>>(hist, dptr, NDRUG);
    scatter_kernel<<<(NEDGE + 255) / 256, 256, 0, stream>>>(dpi_drug, dpi_prot, dptr, cnt, dtmp);
    sortdedup_kernel<<<(NDRUG + 255) / 256, 256, 0, stream>>>(dptr, dtmp, dlist, dcnt);
    base_kernel<<<(NCELL * L0 + 255) / 256, 256, 0, stream>>>(W0, b0, BASE);
    drug_sum_kernel<<<(L0 / CH) * 2, 256, 0, stream>>>(W0, dptr, dcnt, dlist, SA, SB);
    cvtw1_kernel<<<(L1DIM * L0 / 4 + 255) / 256, 256, 0, stream>>>(W1, W1b);
    build_h_kernel<<<BATCH, 256, 0, stream>>>(drug_pairs, cell_lines, SA, SB, BASE, h1);
    gemm_kernel<<<(2 * BATCH / BM) * (L1DIM / BN), 256, 0, stream>>>(h1, W1b, b1, h2,
                                                                     2 * BATCH, L1DIM, L0);
    out_kernel<<<2 * BATCH, 128, 0, stream>>>(h2, W2, b2, out);
}

// Round 4
// 442.917 us; speedup vs baseline: 2.7389x; 1.2748x over previous
//
#include <hip/hip_runtime.h>
#include <hip/hip_bf16.h>
#include <stdint.h>

#define NPROT 19000
#define NDRUG 4000
#define NCELL 16
#define BATCH 4096
#define NEDGE 40000
#define L0 2048
#define L1DIM 1024
#define INDIM 38032
#define HALFDIM 19016

// drug_sum chunking
#define CH 2
#define CHUNK 1024
#define NCHUNK ((NPROT + CHUNK - 1) / CHUNK)   // 19
#define NBUCKET (NCHUNK * 256)                 // 4864

typedef float f32x4 __attribute__((ext_vector_type(4)));
typedef short s16x8 __attribute__((ext_vector_type(8)));

__global__ void zero_int_kernel(int* __restrict__ p, int n) {
    int i = blockIdx.x * 256 + threadIdx.x;
    if (i < n) p[i] = 0;
}

__global__ void hist_kernel(const int* __restrict__ drug, int* __restrict__ hist) {
    int e = blockIdx.x * 256 + threadIdx.x;
    if (e < NEDGE) atomicAdd(&hist[drug[e]], 1);
}

// generic single-block exclusive scan: row_ptr[0..n], row_ptr[n] = total
__global__ __launch_bounds__(256) void scan_kernel(const int* __restrict__ hist,
                                                   int* __restrict__ row_ptr, int n) {
    __shared__ int part[256];
    int t = threadIdx.x;
    int per = (n + 255) / 256;
    int s = 0;
    for (int j = 0; j < per; ++j) {
        int idx = t * per + j;
        if (idx < n) s += hist[idx];
    }
    part[t] = s;
    __syncthreads();
    if (t == 0) {
        int run = 0;
        for (int i = 0; i < 256; ++i) { int v = part[i]; part[i] = run; run += v; }
    }
    __syncthreads();
    int run = part[t];
    for (int j = 0; j < per; ++j) {
        int idx = t * per + j;
        if (idx < n) { row_ptr[idx] = run; run += hist[idx]; }
    }
    if (t == 255) row_ptr[n] = run;
}

// CSR by drug: dtmp[dptr[d] + k] = protein
__global__ void scatter_kernel(const int* __restrict__ drug, const int* __restrict__ prot,
                               const int* __restrict__ dptr, int* __restrict__ cnt,
                               int* __restrict__ dtmp) {
    int e = blockIdx.x * 256 + threadIdx.x;
    if (e < NEDGE) {
        int d = drug[e];
        int pos = dptr[d] + atomicAdd(&cnt[d], 1);
        dtmp[pos] = prot[e];
    }
}

// per-drug: insertion-sort protein list, dedup (reference .set(1.0) semantics)
__global__ void sortdedup_kernel(const int* __restrict__ dptr, int* __restrict__ dtmp,
                                 int* __restrict__ dcnt) {
    int d = blockIdx.x * 256 + threadIdx.x;
    if (d >= NDRUG) return;
    int beg = dptr[d], end = dptr[d + 1];
    for (int i = beg + 1; i < end; ++i) {
        int v = dtmp[i];
        int j = i - 1;
        while (j >= beg && dtmp[j] > v) { dtmp[j + 1] = dtmp[j]; --j; }
        dtmp[j + 1] = v;
    }
    int c = 0, prev = -1;
    for (int i = beg; i < end; ++i) {
        int v = dtmp[i];
        if (v != prev) { dtmp[beg + c] = v; ++c; prev = v; }
    }
    dcnt[d] = c;
}

// count edges per bucket (chunk, owner-thread): b = (p>>10)*256 + (d&255)
__global__ void bucket_count_kernel(const int* __restrict__ dptr, const int* __restrict__ dcnt,
                                    const int* __restrict__ dtmp, int* __restrict__ bcnt) {
    int d = blockIdx.x * 256 + threadIdx.x;
    if (d >= NDRUG) return;
    int beg = dptr[d], end = beg + dcnt[d];
    int town = d & 255;
    for (int i = beg; i < end; ++i) {
        int p = dtmp[i];
        atomicAdd(&bcnt[(p >> 10) * 256 + town], 1);
    }
}

// scatter packed u16 (slot<<10 | p_offset) into bucket-ordered seg stream
__global__ void bucket_scatter_kernel(const int* __restrict__ dptr, const int* __restrict__ dcnt,
                                      const int* __restrict__ dtmp, const int* __restrict__ bptr,
                                      int* __restrict__ bcur, unsigned short* __restrict__ seg) {
    int d = blockIdx.x * 256 + threadIdx.x;
    if (d >= NDRUG) return;
    int beg = dptr[d], end = beg + dcnt[d];
    int town = d & 255;
    int slot = d >> 8;
    for (int i = beg; i < end; ++i) {
        int p = dtmp[i];
        int b = (p >> 10) * 256 + town;
        int pos = bptr[b] + atomicAdd(&bcur[b], 1);
        seg[pos] = (unsigned short)((slot << 10) | (p & 1023));
    }
}

// BASE[c][ch] = b0[ch] + W0[ch, 19000+c] + W0[ch, 38016+c]
__global__ void base_kernel(const float* __restrict__ W0, const float* __restrict__ b0,
                            float* __restrict__ BASE) {
    int i = blockIdx.x * 256 + threadIdx.x;
    if (i < NCELL * L0) {
        int c = i >> 11, ch = i & 2047;
        const float* wr = W0 + (size_t)ch * INDIM;
        BASE[(size_t)c * L0 + ch] = b0[ch] + wr[NPROT + c] + wr[HALFDIM + NPROT + c];
    }
}

// Atomic-free drug sum, precomputed walk.
// Block owns CH=2 channels of one half (XCD-swizzled). Edges counting-sorted
// by (chunk, owner-thread); each thread streams its contiguous segment and
// accumulates into exclusive LDS slots acc[d*2+c] (owner t = d&255).
__global__ __launch_bounds__(256) void drug_sum_kernel(const float* __restrict__ W0,
                                                       const int* __restrict__ bptr,
                                                       const unsigned short* __restrict__ seg,
                                                       float* __restrict__ SA,
                                                       float* __restrict__ SB) {
    __shared__ float wst[2][CH][CHUNK];   // 16 KB
    __shared__ float acc[NDRUG * 2];      // 32 KB
    int t = threadIdx.x;
    int bid = blockIdx.x;
    // XCD swizzle: same-XCD blocks cover consecutive chpairs -> shared L2 lines
    int j = bid & 7, i = bid >> 3;
    int hb = (i >> 7) & 1;
    int chpair = (j << 7) + (i & 127);
    int ch0 = chpair * 2;
    size_t colbase = (size_t)hb * HALFDIM;

    for (int k = t; k < NDRUG * 2; k += 256) acc[k] = 0.f;

    auto stage = [&](int buf, int p0, int pc) {
#pragma unroll
        for (int c = 0; c < CH; ++c) {
            const float* src = W0 + (size_t)(ch0 + c) * INDIM + colbase + p0;
            if (t * 4 < pc) {
                __builtin_amdgcn_global_load_lds(
                    (const __attribute__((address_space(1))) void*)(src + t * 4),
                    (__attribute__((address_space(3))) void*)(&wst[buf][c][t * 4]), 16, 0, 0);
            }
        }
    };
    stage(0, 0, CHUNK);
    __syncthreads();

    for (int cidx = 0; cidx < NCHUNK; ++cidx) {
        int p0 = cidx * CHUNK;
        int buf = cidx & 1;
        if (cidx + 1 < NCHUNK) {
            int np0 = p0 + CHUNK;
            stage(buf ^ 1, np0, min(CHUNK, NPROT - np0));
        }
        const float* w0s = wst[buf][0];
        const float* w1s = wst[buf][1];
        int b = (cidx << 8) + t;
        int ib = bptr[b], ie = bptr[b + 1];
        for (; ib < ie; ++ib) {
            unsigned v = seg[ib];
            int p = v & 1023;
            int d = (((int)v >> 10) << 8) | t;
            float x = w0s[p];
            float y = w1s[p];
            float2 a = *(float2*)&acc[d * 2];
            a.x += x;
            a.y += y;
            *(float2*)&acc[d * 2] = a;
        }
        __syncthreads();  // drains staged vmcnt + protects buf reuse
    }

    float* dst = hb ? SB : SA;
    for (int d = t; d < NDRUG; d += 256) {
        float2 v = *(float2*)&acc[d * 2];
        *(float2*)(dst + (size_t)d * L0 + ch0) = v;
    }
}

__global__ void cvtw1_kernel(const float* __restrict__ W1, __hip_bfloat16* __restrict__ W1b) {
    int i = blockIdx.x * 256 + threadIdx.x;  // one float4 each
    const int n = L1DIM * L0 / 4;
    if (i < n) {
        float4 v = ((const float4*)W1)[i];
        union { ushort4 u; __hip_bfloat16 h[4]; } pk;
        pk.h[0] = __float2bfloat16(v.x);
        pk.h[1] = __float2bfloat16(v.y);
        pk.h[2] = __float2bfloat16(v.z);
        pk.h[3] = __float2bfloat16(v.w);
        ((ushort4*)W1b)[i] = pk.u;
    }
}

// h1[b]      = relu(BASE[c] + SA[d1] + SB[d2])  (x1)
// h1[4096+b] = relu(BASE[c] + SA[d2] + SB[d1])  (x2)
__global__ __launch_bounds__(256) void build_h_kernel(const int* __restrict__ dp,
                                                      const int* __restrict__ cl,
                                                      const float* __restrict__ SA,
                                                      const float* __restrict__ SB,
                                                      const float* __restrict__ BASE,
                                                      __hip_bfloat16* __restrict__ h1) {
    int b = blockIdx.x;
    int d1 = dp[2 * b], d2 = dp[2 * b + 1], c = cl[b];
    const float* bs = BASE + (size_t)c * L0;
    const float* a1 = SA + (size_t)d1 * L0;
    const float* a2 = SA + (size_t)d2 * L0;
    const float* s1 = SB + (size_t)d1 * L0;
    const float* s2 = SB + (size_t)d2 * L0;
    for (int ch = threadIdx.x * 4; ch < L0; ch += 1024) {
        float4 vb = *(const float4*)(bs + ch);
        float4 va1 = *(const float4*)(a1 + ch);
        float4 va2 = *(const float4*)(a2 + ch);
        float4 vs1 = *(const float4*)(s1 + ch);
        float4 vs2 = *(const float4*)(s2 + ch);
        union { ushort4 u; __hip_bfloat16 h[4]; } p1, p2;
        const float* fb = (const float*)&vb;
        const float* fa1 = (const float*)&va1;
        const float* fa2 = (const float*)&va2;
        const float* fs1 = (const float*)&vs1;
        const float* fs2 = (const float*)&vs2;
#pragma unroll
        for (int j = 0; j < 4; ++j) {
            float z1 = fb[j] + fa1[j] + fs2[j];
            float z2 = fb[j] + fa2[j] + fs1[j];
            p1.h[j] = __float2bfloat16(fmaxf(z1, 0.f));
            p2.h[j] = __float2bfloat16(fmaxf(z2, 0.f));
        }
        *(ushort4*)((__hip_bfloat16*)h1 + (size_t)b * L0 + ch) = p1.u;
        *(ushort4*)((__hip_bfloat16*)h1 + (size_t)(BATCH + b) * L0 + ch) = p2.u;
    }
}

// C = relu(A @ B^T + bias), A: MxK bf16, B: NxK bf16 (W1), C: MxN bf16
#define BM 128
#define BN 128
#define BKK 32
__global__ __launch_bounds__(256) void gemm_kernel(const __hip_bfloat16* __restrict__ A,
                                                   const __hip_bfloat16* __restrict__ B,
                                                   const float* __restrict__ bias,
                                                   __hip_bfloat16* __restrict__ C,
                                                   int M, int N, int K) {
    __shared__ __hip_bfloat16 As[BM * BKK];
    __shared__ __hip_bfloat16 Bs[BN * BKK];
    int t = threadIdx.x;
    int ntiles = N / BN;
    int bx = blockIdx.x % ntiles;
    int by = blockIdx.x / ntiles;
    int brow = by * BM, bcol = bx * BN;
    int w = t >> 6, l = t & 63;
    int wr = w >> 1, wc = w & 1;
    f32x4 acc[4][4] = {};
    int row = l & 15, ko = (l >> 4) * 8;
    for (int k0 = 0; k0 < K; k0 += BKK) {
#pragma unroll
        for (int i = 0; i < 2; ++i) {
            int idx = i * 256 + t;
            int r = idx >> 2, cb = (idx & 3) * 8;
            __builtin_amdgcn_global_load_lds(
                (const __attribute__((address_space(1))) void*)(A + (size_t)(brow + r) * K + k0 + cb),
                (__attribute__((address_space(3))) void*)(&As[idx * 8]), 16, 0, 0);
            __builtin_amdgcn_global_load_lds(
                (const __attribute__((address_space(1))) void*)(B + (size_t)(bcol + r) * K + k0 + cb),
                (__attribute__((address_space(3))) void*)(&Bs[idx * 8]), 16, 0, 0);
        }
        __syncthreads();
        s16x8 af[4], bfr[4];
#pragma unroll
        for (int m = 0; m < 4; ++m)
            af[m] = *(const s16x8*)(&As[(wr * 64 + m * 16 + row) * BKK + ko]);
#pragma unroll
        for (int n = 0; n < 4; ++n)
            bfr[n] = *(const s16x8*)(&Bs[(wc * 64 + n * 16 + row) * BKK + ko]);
#pragma unroll
        for (int m = 0; m < 4; ++m)
#pragma unroll
            for (int n = 0; n < 4; ++n)
                acc[m][n] = __builtin_amdgcn_mfma_f32_16x16x32_bf16(af[m], bfr[n], acc[m][n], 0, 0, 0);
        __syncthreads();
    }
    int cr = (l >> 4) * 4;
    int cc = l & 15;
#pragma unroll
    for (int m = 0; m < 4; ++m)
#pragma unroll
        for (int n = 0; n < 4; ++n) {
#pragma unroll
            for (int j = 0; j < 4; ++j) {
                int grow = brow + wr * 64 + m * 16 + cr + j;
                int gcol = bcol + wc * 64 + n * 16 + cc;
                float v = acc[m][n][j] + bias[gcol];
                C[(size_t)grow * N + gcol] = __float2bfloat16(fmaxf(v, 0.f));
            }
        }
}

// out[r] = b2 + sum_o h2[r][o] * W2[o]
__global__ __launch_bounds__(128) void out_kernel(const __hip_bfloat16* __restrict__ h2,
                                                  const float* __restrict__ W2,
                                                  const float* __restrict__ b2,
                                                  float* __restrict__ out) {
    int r = blockIdx.x;
    int t = threadIdx.x;
    union { uint4 u; __hip_bfloat16 h[8]; } pk;
    pk.u = *(const uint4*)(h2 + (size_t)r * L1DIM + t * 8);
    float s = 0.f;
#pragma unroll
    for (int j = 0; j < 8; ++j) s += __bfloat162float(pk.h[j]) * W2[t * 8 + j];
    for (int o = 32; o > 0; o >>= 1) s += __shfl_down(s, o);
    __shared__ float red[2];
    if ((t & 63) == 0) red[t >> 6] = s;
    __syncthreads();
    if (t == 0) out[r] = red[0] + red[1] + b2[0];
}

extern "C" void kernel_launch(void* const* d_in, const int* in_sizes, int n_in,
                              void* d_out, int out_size, void* d_ws, size_t ws_size,
                              hipStream_t stream) {
    const int* drug_pairs = (const int*)d_in[0];
    const int* cell_lines = (const int*)d_in[1];
    const int* dpi_drug = (const int*)d_in[2];
    const int* dpi_prot = (const int*)d_in[3];
    const float* W0 = (const float*)d_in[4];
    const float* b0 = (const float*)d_in[5];
    const float* W1 = (const float*)d_in[6];
    const float* b1 = (const float*)d_in[7];
    const float* W2 = (const float*)d_in[8];
    const float* b2 = (const float*)d_in[9];
    float* out = (float*)d_out;

    char* ws = (char*)d_ws;
    size_t off = 0;
    auto alloc = [&](size_t bytes) {
        char* p = ws + off;
        off += (bytes + 255) & ~(size_t)255;
        return p;
    };
    float* SA = (float*)alloc((size_t)NDRUG * L0 * 4);
    float* SB = (float*)alloc((size_t)NDRUG * L0 * 4);
    float* BASE = (float*)alloc((size_t)NCELL * L0 * 4);
    __hip_bfloat16* W1b = (__hip_bfloat16*)alloc((size_t)L1DIM * L0 * 2);
    __hip_bfloat16* h1 = (__hip_bfloat16*)alloc((size_t)2 * BATCH * L0 * 2);
    __hip_bfloat16* h2 = (__hip_bfloat16*)alloc((size_t)2 * BATCH * L1DIM * 2);
    int* hist = (int*)alloc((size_t)NDRUG * 4);
    int* cnt = (int*)alloc((size_t)NDRUG * 4);
    int* dptr = (int*)alloc((size_t)(NDRUG + 1) * 4);
    int* dtmp = (int*)alloc((size_t)NEDGE * 4);
    int* dcnt = (int*)alloc((size_t)NDRUG * 4);
    int* bcnt = (int*)alloc((size_t)NBUCKET * 4);
    int* bcur = (int*)alloc((size_t)NBUCKET * 4);
    int* bptr = (int*)alloc((size_t)(NBUCKET + 1) * 4);
    unsigned short* seg = (unsigned short*)alloc((size_t)NEDGE * 2);

    zero_int_kernel<<<(NDRUG + 255) / 256, 256, 0, stream>>>(hist, NDRUG);
    zero_int_kernel<<<(NDRUG + 255) / 256, 256, 0, stream>>>(cnt, NDRUG);
    zero_int_kernel<<<(NBUCKET + 255) / 256, 256, 0, stream>>>(bcnt, NBUCKET);
    zero_int_kernel<<<(NBUCKET + 255) / 256, 256, 0, stream>>>(bcur, NBUCKET);
    hist_kernel<<<(NEDGE + 255) / 256, 256, 0, stream>>>(dpi_drug, hist);
    scan_kernel<<<1, 256, 0, stream>>>(hist, dptr, NDRUG);
    scatter_kernel<<<(NEDGE + 255) / 256, 256, 0, stream>>>(dpi_drug, dpi_prot, dptr, cnt, dtmp);
    sortdedup_kernel<<<(NDRUG + 255) / 256, 256, 0, stream>>>(dptr, dtmp, dcnt);
    bucket_count_kernel<<<(NDRUG + 255) / 256, 256, 0, stream>>>(dptr, dcnt, dtmp, bcnt);
    scan_kernel<<<1, 256, 0, stream>>>(bcnt, bptr, NBUCKET);
    bucket_scatter_kernel<<<(NDRUG + 255) / 256, 256, 0, stream>>>(dptr, dcnt, dtmp, bptr, bcur, seg);
    base_kernel<<<(NCELL * L0 + 255) / 256, 256, 0, stream>>>(W0, b0, BASE);
    drug_sum_kernel<<<(L0 / CH) * 2, 256, 0, stream>>>(W0, bptr, seg, SA, SB);
    cvtw1_kernel<<<(L1DIM * L0 / 4 + 255) / 256, 256, 0, stream>>>(W1, W1b);
    build_h_kernel<<<BATCH, 256, 0, stream>>>(drug_pairs, cell_lines, SA, SB, BASE, h1);
    gemm_kernel<<<(2 * BATCH / BM) * (L1DIM / BN), 256, 0, stream>>>(h1, W1b, b1, h2,
                                                                     2 * BATCH, L1DIM, L0);
    out_kernel<<<2 * BATCH, 128, 0, stream>>>(h2, W2, b2, out);
}

// Round 6
// 415.629 us; speedup vs baseline: 2.9188x; 1.0657x over previous
//
#include <hip/hip_runtime.h>
#include <hip/hip_bf16.h>
#include <stdint.h>

#define NPROT 19000
#define NDRUG 4000
#define NCELL 16
#define BATCH 4096
#define NEDGE 40000
#define L0 2048
#define L1DIM 1024
#define INDIM 38032
#define HALFDIM 19016

// drug_sum chunking
#define CH 2
#define CHUNK 1024
#define NCHUNK ((NPROT + CHUNK - 1) / CHUNK)   // 19
#define NBUCKET (NCHUNK * 256)                 // 4864

typedef float f32x4 __attribute__((ext_vector_type(4)));
typedef short s16x8 __attribute__((ext_vector_type(8)));

__global__ void zero_all_kernel(int* __restrict__ p, int n) {
    int i = blockIdx.x * 256 + threadIdx.x;
    if (i < n) p[i] = 0;
}

__global__ void hist_kernel(const int* __restrict__ drug, int* __restrict__ hist) {
    int e = blockIdx.x * 256 + threadIdx.x;
    if (e < NEDGE) atomicAdd(&hist[drug[e]], 1);
}

// generic single-block exclusive scan: row_ptr[0..n], row_ptr[n] = total
__global__ __launch_bounds__(256) void scan_kernel(const int* __restrict__ hist,
                                                   int* __restrict__ row_ptr, int n) {
    __shared__ int part[256];
    int t = threadIdx.x;
    int per = (n + 255) / 256;
    int s = 0;
    for (int j = 0; j < per; ++j) {
        int idx = t * per + j;
        if (idx < n) s += hist[idx];
    }
    part[t] = s;
    __syncthreads();
    if (t == 0) {
        int run = 0;
        for (int i = 0; i < 256; ++i) { int v = part[i]; part[i] = run; run += v; }
    }
    __syncthreads();
    int run = part[t];
    for (int j = 0; j < per; ++j) {
        int idx = t * per + j;
        if (idx < n) { row_ptr[idx] = run; run += hist[idx]; }
    }
    if (t == 255) row_ptr[n] = run;
}

// CSR by drug: dtmp[dptr[d] + k] = protein
__global__ void scatter_kernel(const int* __restrict__ drug, const int* __restrict__ prot,
                               const int* __restrict__ dptr, int* __restrict__ cnt,
                               int* __restrict__ dtmp) {
    int e = blockIdx.x * 256 + threadIdx.x;
    if (e < NEDGE) {
        int d = drug[e];
        int pos = dptr[d] + atomicAdd(&cnt[d], 1);
        dtmp[pos] = prot[e];
    }
}

// per-drug: insertion-sort protein list, dedup (reference .set(1.0) semantics),
// then count edges per bucket (chunk, owner-thread): b = (p>>10)*256 + (d&255)
__global__ void sortdedup_kernel(const int* __restrict__ dptr, int* __restrict__ dtmp,
                                 int* __restrict__ dcnt, int* __restrict__ bcnt) {
    int d = blockIdx.x * 256 + threadIdx.x;
    if (d >= NDRUG) return;
    int beg = dptr[d], end = dptr[d + 1];
    for (int i = beg + 1; i < end; ++i) {
        int v = dtmp[i];
        int j = i - 1;
        while (j >= beg && dtmp[j] > v) { dtmp[j + 1] = dtmp[j]; --j; }
        dtmp[j + 1] = v;
    }
    int c = 0, prev = -1;
    for (int i = beg; i < end; ++i) {
        int v = dtmp[i];
        if (v != prev) { dtmp[beg + c] = v; ++c; prev = v; }
    }
    dcnt[d] = c;
    int town = d & 255;
    for (int i = beg; i < beg + c; ++i)
        atomicAdd(&bcnt[(dtmp[i] >> 10) * 256 + town], 1);
}

// scatter packed u16 (slot<<10 | p_offset) into bucket-ordered seg stream
__global__ void bucket_scatter_kernel(const int* __restrict__ dptr, const int* __restrict__ dcnt,
                                      const int* __restrict__ dtmp, const int* __restrict__ bptr,
                                      int* __restrict__ bcur, unsigned short* __restrict__ seg) {
    int d = blockIdx.x * 256 + threadIdx.x;
    if (d >= NDRUG) return;
    int beg = dptr[d], end = beg + dcnt[d];
    int town = d & 255;
    int slot = d >> 8;
    for (int i = beg; i < end; ++i) {
        int p = dtmp[i];
        int b = (p >> 10) * 256 + town;
        int pos = bptr[b] + atomicAdd(&bcur[b], 1);
        seg[pos] = (unsigned short)((slot << 10) | (p & 1023));
    }
}

// BASE[c][ch] = b0[ch] + W0[ch, 19000+c] + W0[ch, 38016+c]
__global__ void base_kernel(const float* __restrict__ W0, const float* __restrict__ b0,
                            float* __restrict__ BASE) {
    int i = blockIdx.x * 256 + threadIdx.x;
    if (i < NCELL * L0) {
        int c = i >> 11, ch = i & 2047;
        const float* wr = W0 + (size_t)ch * INDIM;
        BASE[(size_t)c * L0 + ch] = b0[ch] + wr[NPROT + c] + wr[HALFDIM + NPROT + c];
    }
}

// Atomic-free drug sum, precomputed walk, batch-4 pipelined edge loop.
// Block owns CH=2 channels of one half (XCD-swizzled). Edges counting-sorted
// by (chunk, owner-thread); each thread streams its contiguous segment and
// accumulates into exclusive LDS slots acc[d*2+c] (owner t = d&255).
__global__ __launch_bounds__(256) void drug_sum_kernel(const float* __restrict__ W0,
                                                       const int* __restrict__ bptr,
                                                       const unsigned short* __restrict__ seg,
                                                       float* __restrict__ SA,
                                                       float* __restrict__ SB) {
    __shared__ float wst[2][CH][CHUNK];   // 16 KB
    __shared__ float acc[NDRUG * 2];      // 32 KB
    int t = threadIdx.x;
    int bid = blockIdx.x;
    // XCD swizzle: same-XCD blocks cover consecutive chpairs -> shared L2 lines
    int j = bid & 7, i = bid >> 3;
    int hb = (i >> 7) & 1;
    int chpair = (j << 7) + (i & 127);
    int ch0 = chpair * 2;
    size_t colbase = (size_t)hb * HALFDIM;

    for (int k = t; k < NDRUG * 2; k += 256) acc[k] = 0.f;

    auto stage = [&](int buf, int p0, int pc) {
#pragma unroll
        for (int c = 0; c < CH; ++c) {
            const float* src = W0 + (size_t)(ch0 + c) * INDIM + colbase + p0;
            if (t * 4 < pc) {
                __builtin_amdgcn_global_load_lds(
                    (const __attribute__((address_space(1))) void*)(src + t * 4),
                    (__attribute__((address_space(3))) void*)(&wst[buf][c][t * 4]), 16, 0, 0);
            }
        }
    };
    stage(0, 0, CHUNK);
    __syncthreads();

    for (int cidx = 0; cidx < NCHUNK; ++cidx) {
        int buf = cidx & 1;
        if (cidx + 1 < NCHUNK) {
            int np0 = (cidx + 1) * CHUNK;
            stage(buf ^ 1, np0, min(CHUNK, NPROT - np0));
        }
        const float* w0s = wst[buf][0];
        const float* w1s = wst[buf][1];
        int b = (cidx << 8) + t;
        int ib = bptr[b], ie = bptr[b + 1];
        // batch-4: independent seg loads + ds_reads pipeline; acc RMWs stay in
        // program order (may-alias) so same-drug duplicates remain correct.
        for (; ib + 4 <= ie; ib += 4) {
            unsigned v0 = seg[ib + 0], v1 = seg[ib + 1], v2 = seg[ib + 2], v3 = seg[ib + 3];
            int p0_ = v0 & 1023, p1_ = v1 & 1023, p2_ = v2 & 1023, p3_ = v3 & 1023;
            int d0 = (((int)v0 >> 10) << 8) | t;
            int d1 = (((int)v1 >> 10) << 8) | t;
            int d2 = (((int)v2 >> 10) << 8) | t;
            int d3 = (((int)v3 >> 10) << 8) | t;
            float x0 = w0s[p0_], y0 = w1s[p0_];
            float x1 = w0s[p1_], y1 = w1s[p1_];
            float x2 = w0s[p2_], y2 = w1s[p2_];
            float x3 = w0s[p3_], y3 = w1s[p3_];
            float2 a;
            a = *(float2*)&acc[d0 * 2]; a.x += x0; a.y += y0; *(float2*)&acc[d0 * 2] = a;
            a = *(float2*)&acc[d1 * 2]; a.x += x1; a.y += y1; *(float2*)&acc[d1 * 2] = a;
            a = *(float2*)&acc[d2 * 2]; a.x += x2; a.y += y2; *(float2*)&acc[d2 * 2] = a;
            a = *(float2*)&acc[d3 * 2]; a.x += x3; a.y += y3; *(float2*)&acc[d3 * 2] = a;
        }
        if (ib + 2 <= ie) {
            unsigned v0 = seg[ib + 0], v1 = seg[ib + 1];
            int p0_ = v0 & 1023, p1_ = v1 & 1023;
            int d0 = (((int)v0 >> 10) << 8) | t;
            int d1 = (((int)v1 >> 10) << 8) | t;
            float x0 = w0s[p0_], y0 = w1s[p0_];
            float x1 = w0s[p1_], y1 = w1s[p1_];
            float2 a;
            a = *(float2*)&acc[d0 * 2]; a.x += x0; a.y += y0; *(float2*)&acc[d0 * 2] = a;
            a = *(float2*)&acc[d1 * 2]; a.x += x1; a.y += y1; *(float2*)&acc[d1 * 2] = a;
            ib += 2;
        }
        if (ib < ie) {
            unsigned v0 = seg[ib];
            int p0_ = v0 & 1023;
            int d0 = (((int)v0 >> 10) << 8) | t;
            float x0 = w0s[p0_], y0 = w1s[p0_];
            float2 a;
            a = *(float2*)&acc[d0 * 2]; a.x += x0; a.y += y0; *(float2*)&acc[d0 * 2] = a;
        }
        __syncthreads();  // drains staged vmcnt + protects buf reuse
    }

    float* dst = hb ? SB : SA;
    for (int d = t; d < NDRUG; d += 256) {
        float2 v = *(float2*)&acc[d * 2];
        *(float2*)(dst + (size_t)d * L0 + ch0) = v;
    }
}

__global__ void cvtw1_kernel(const float* __restrict__ W1, __hip_bfloat16* __restrict__ W1b) {
    int i = blockIdx.x * 256 + threadIdx.x;  // one float4 each
    const int n = L1DIM * L0 / 4;
    if (i < n) {
        float4 v = ((const float4*)W1)[i];
        union { ushort4 u; __hip_bfloat16 h[4]; } pk;
        pk.h[0] = __float2bfloat16(v.x);
        pk.h[1] = __float2bfloat16(v.y);
        pk.h[2] = __float2bfloat16(v.z);
        pk.h[3] = __float2bfloat16(v.w);
        ((ushort4*)W1b)[i] = pk.u;
    }
}

// h1[b]      = relu(BASE[c] + SA[d1] + SB[d2])  (x1)
// h1[4096+b] = relu(BASE[c] + SA[d2] + SB[d1])  (x2)
__global__ __launch_bounds__(256) void build_h_kernel(const int* __restrict__ dp,
                                                      const int* __restrict__ cl,
                                                      const float* __restrict__ SA,
                                                      const float* __restrict__ SB,
                                                      const float* __restrict__ BASE,
                                                      __hip_bfloat16* __restrict__ h1) {
    int b = blockIdx.x;
    int d1 = dp[2 * b], d2 = dp[2 * b + 1], c = cl[b];
    const float* bs = BASE + (size_t)c * L0;
    const float* a1 = SA + (size_t)d1 * L0;
    const float* a2 = SA + (size_t)d2 * L0;
    const float* s1 = SB + (size_t)d1 * L0;
    const float* s2 = SB + (size_t)d2 * L0;
    for (int ch = threadIdx.x * 4; ch < L0; ch += 1024) {
        float4 vb = *(const float4*)(bs + ch);
        float4 va1 = *(const float4*)(a1 + ch);
        float4 va2 = *(const float4*)(a2 + ch);
        float4 vs1 = *(const float4*)(s1 + ch);
        float4 vs2 = *(const float4*)(s2 + ch);
        union { ushort4 u; __hip_bfloat16 h[4]; } p1, p2;
        const float* fb = (const float*)&vb;
        const float* fa1 = (const float*)&va1;
        const float* fa2 = (const float*)&va2;
        const float* fs1 = (const float*)&vs1;
        const float* fs2 = (const float*)&vs2;
#pragma unroll
        for (int j = 0; j < 4; ++j) {
            float z1 = fb[j] + fa1[j] + fs2[j];
            float z2 = fb[j] + fa2[j] + fs1[j];
            p1.h[j] = __float2bfloat16(fmaxf(z1, 0.f));
            p2.h[j] = __float2bfloat16(fmaxf(z2, 0.f));
        }
        *(ushort4*)((__hip_bfloat16*)h1 + (size_t)b * L0 + ch) = p1.u;
        *(ushort4*)((__hip_bfloat16*)h1 + (size_t)(BATCH + b) * L0 + ch) = p2.u;
    }
}

// C = relu(A @ B^T + bias), A: MxK bf16, B: NxK bf16 (W1), C: MxN bf16
#define BM 128
#define BN 128
#define BKK 32
__global__ __launch_bounds__(256) void gemm_kernel(const __hip_bfloat16* __restrict__ A,
                                                   const __hip_bfloat16* __restrict__ B,
                                                   const float* __restrict__ bias,
                                                   __hip_bfloat16* __restrict__ C,
                                                   int M, int N, int K) {
    __shared__ __hip_bfloat16 As[BM * BKK];
    __shared__ __hip_bfloat16 Bs[BN * BKK];
    int t = threadIdx.x;
    int ntiles = N / BN;
    int bx = blockIdx.x % ntiles;
    int by = blockIdx.x / ntiles;
    int brow = by * BM, bcol = bx * BN;
    int w = t >> 6, l = t & 63;
    int wr = w >> 1, wc = w & 1;
    f32x4 acc[4][4] = {};
    int row = l & 15, ko = (l >> 4) * 8;
    for (int k0 = 0; k0 < K; k0 += BKK) {
#pragma unroll
        for (int i = 0; i < 2; ++i) {
            int idx = i * 256 + t;
            int r = idx >> 2, cb = (idx & 3) * 8;
            __builtin_amdgcn_global_load_lds(
                (const __attribute__((address_space(1))) void*)(A + (size_t)(brow + r) * K + k0 + cb),
                (__attribute__((address_space(3))) void*)(&As[idx * 8]), 16, 0, 0);
            __builtin_amdgcn_global_load_lds(
                (const __attribute__((address_space(1))) void*)(B + (size_t)(bcol + r) * K + k0 + cb),
                (__attribute__((address_space(3))) void*)(&Bs[idx * 8]), 16, 0, 0);
        }
        __syncthreads();
        s16x8 af[4], bfr[4];
#pragma unroll
        for (int m = 0; m < 4; ++m)
            af[m] = *(const s16x8*)(&As[(wr * 64 + m * 16 + row) * BKK + ko]);
#pragma unroll
        for (int n = 0; n < 4; ++n)
            bfr[n] = *(const s16x8*)(&Bs[(wc * 64 + n * 16 + row) * BKK + ko]);
#pragma unroll
        for (int m = 0; m < 4; ++m)
#pragma unroll
            for (int n = 0; n < 4; ++n)
                acc[m][n] = __builtin_amdgcn_mfma_f32_16x16x32_bf16(af[m], bfr[n], acc[m][n], 0, 0, 0);
        __syncthreads();
    }
    int cr = (l >> 4) * 4;
    int cc = l & 15;
#pragma unroll
    for (int m = 0; m < 4; ++m)
#pragma unroll
        for (int n = 0; n < 4; ++n) {
#pragma unroll
            for (int j = 0; j < 4; ++j) {
                int grow = brow + wr * 64 + m * 16 + cr + j;
                int gcol = bcol + wc * 64 + n * 16 + cc;
                float v = acc[m][n][j] + bias[gcol];
                C[(size_t)grow * N + gcol] = __float2bfloat16(fmaxf(v, 0.f));
            }
        }
}

// out[r] = b2 + sum_o h2[r][o] * W2[o]
__global__ __launch_bounds__(128) void out_kernel(const __hip_bfloat16* __restrict__ h2,
                                                  const float* __restrict__ W2,
                                                  const float* __restrict__ b2,
                                                  float* __restrict__ out) {
    int r = blockIdx.x;
    int t = threadIdx.x;
    union { uint4 u; __hip_bfloat16 h[8]; } pk;
    pk.u = *(const uint4*)(h2 + (size_t)r * L1DIM + t * 8);
    float s = 0.f;
#pragma unroll
    for (int j = 0; j < 8; ++j) s += __bfloat162float(pk.h[j]) * W2[t * 8 + j];
    for (int o = 32; o > 0; o >>= 1) s += __shfl_down(s, o);
    __shared__ float red[2];
    if ((t & 63) == 0) red[t >> 6] = s;
    __syncthreads();
    if (t == 0) out[r] = red[0] + red[1] + b2[0];
}

extern "C" void kernel_launch(void* const* d_in, const int* in_sizes, int n_in,
                              void* d_out, int out_size, void* d_ws, size_t ws_size,
                              hipStream_t stream) {
    const int* drug_pairs = (const int*)d_in[0];
    const int* cell_lines = (const int*)d_in[1];
    const int* dpi_drug = (const int*)d_in[2];
    const int* dpi_prot = (const int*)d_in[3];
    const float* W0 = (const float*)d_in[4];
    const float* b0 = (const float*)d_in[5];
    const float* W1 = (const float*)d_in[6];
    const float* b1 = (const float*)d_in[7];
    const float* W2 = (const float*)d_in[8];
    const float* b2 = (const float*)d_in[9];
    float* out = (float*)d_out;

    char* ws = (char*)d_ws;
    size_t off = 0;
    auto alloc = [&](size_t bytes) {
        char* p = ws + off;
        off += (bytes + 255) & ~(size_t)255;
        return p;
    };
    float* SA = (float*)alloc((size_t)NDRUG * L0 * 4);
    float* SB = (float*)alloc((size_t)NDRUG * L0 * 4);
    float* BASE = (float*)alloc((size_t)NCELL * L0 * 4);
    __hip_bfloat16* W1b = (__hip_bfloat16*)alloc((size_t)L1DIM * L0 * 2);
    __hip_bfloat16* h1 = (__hip_bfloat16*)alloc((size_t)2 * BATCH * L0 * 2);
    __hip_bfloat16* h2 = (__hip_bfloat16*)alloc((size_t)2 * BATCH * L1DIM * 2);
    // contiguous zero region: hist, cnt, bcnt, bcur
    const int ZREG_N = 2 * NDRUG + 2 * NBUCKET;
    int* zreg = (int*)alloc((size_t)ZREG_N * 4);
    int* hist = zreg;
    int* cnt = zreg + NDRUG;
    int* bcnt = zreg + 2 * NDRUG;
    int* bcur = zreg + 2 * NDRUG + NBUCKET;
    int* dptr = (int*)alloc((size_t)(NDRUG + 1) * 4);
    int* dtmp = (int*)alloc((size_t)NEDGE * 4);
    int* dcnt = (int*)alloc((size_t)NDRUG * 4);
    int* bptr = (int*)alloc((size_t)(NBUCKET + 1) * 4);
    unsigned short* seg = (unsigned short*)alloc((size_t)NEDGE * 2);

    zero_all_kernel<<<(ZREG_N + 255) / 256, 256, 0, stream>>>(zreg, ZREG_N);
    hist_kernel<<<(NEDGE + 255) / 256, 256, 0, stream>>>(dpi_drug, hist);
    scan_kernel<<<1, 256, 0, stream>>>(hist, dptr, NDRUG);
    scatter_kernel<<<(NEDGE + 255) / 256, 256, 0, stream>>>(dpi_drug, dpi_prot, dptr, cnt, dtmp);
    sortdedup_kernel<<<(NDRUG + 255) / 256, 256, 0, stream>>>(dptr, dtmp, dcnt, bcnt);
    scan_kernel<<<1, 256, 0, stream>>>(bcnt, bptr, NBUCKET);
    bucket_scatter_kernel<<<(NDRUG + 255) / 256, 256, 0, stream>>>(dptr, dcnt, dtmp, bptr, bcur, seg);
    base_kernel<<<(NCELL * L0 + 255) / 256, 256, 0, stream>>>(W0, b0, BASE);
    drug_sum_kernel<<<(L0 / CH) * 2, 256, 0, stream>>>(W0, bptr, seg, SA, SB);
    cvtw1_kernel<<<(L1DIM * L0 / 4 + 255) / 256, 256, 0, stream>>>(W1, W1b);
    build_h_kernel<<<BATCH, 256, 0, stream>>>(drug_pairs, cell_lines, SA, SB, BASE, h1);
    gemm_kernel<<<(2 * BATCH / BM) * (L1DIM / BN), 256, 0, stream>>>(h1, W1b, b1, h2,
                                                                     2 * BATCH, L1DIM, L0);
    out_kernel<<<2 * BATCH, 128, 0, stream>>>(h2, W2, b2, out);
}

// Round 7
// 369.661 us; speedup vs baseline: 3.2817x; 1.1244x over previous
//
#include <hip/hip_runtime.h>
#include <hip/hip_bf16.h>
#include <stdint.h>

#define NPROT 19000
#define NDRUG 4000
#define NCELL 16
#define BATCH 4096
#define NEDGE 40000
#define L0 2048
#define L1DIM 1024
#define INDIM 38032
#define HALFDIM 19016
#define WSTN 19008   // 19000 + 8 zero pad (dummy slot at 19000)

typedef float f32x4 __attribute__((ext_vector_type(4)));
typedef short s16x8 __attribute__((ext_vector_type(8)));

__global__ void zero_all_kernel(int* __restrict__ p, int n) {
    int i = blockIdx.x * 256 + threadIdx.x;
    if (i < n) p[i] = 0;
}

__global__ void hist_kernel(const int* __restrict__ drug, int* __restrict__ hist) {
    int e = blockIdx.x * 256 + threadIdx.x;
    if (e < NEDGE) atomicAdd(&hist[drug[e]], 1);
}

// generic single-block exclusive scan: row_ptr[0..n], row_ptr[n] = total
__global__ __launch_bounds__(256) void scan_kernel(const int* __restrict__ hist,
                                                   int* __restrict__ row_ptr, int n) {
    __shared__ int part[256];
    int t = threadIdx.x;
    int per = (n + 255) / 256;
    int s = 0;
    for (int j = 0; j < per; ++j) {
        int idx = t * per + j;
        if (idx < n) s += hist[idx];
    }
    part[t] = s;
    __syncthreads();
    if (t == 0) {
        int run = 0;
        for (int i = 0; i < 256; ++i) { int v = part[i]; part[i] = run; run += v; }
    }
    __syncthreads();
    int run = part[t];
    for (int j = 0; j < per; ++j) {
        int idx = t * per + j;
        if (idx < n) { row_ptr[idx] = run; run += hist[idx]; }
    }
    if (t == 255) row_ptr[n] = run;
}

// CSR by drug: dtmp[dptr[d] + k] = protein
__global__ void scatter_kernel(const int* __restrict__ drug, const int* __restrict__ prot,
                               const int* __restrict__ dptr, int* __restrict__ cnt,
                               int* __restrict__ dtmp) {
    int e = blockIdx.x * 256 + threadIdx.x;
    if (e < NEDGE) {
        int d = drug[e];
        int pos = dptr[d] + atomicAdd(&cnt[d], 1);
        dtmp[pos] = prot[e];
    }
}

// per-drug: insertion-sort protein list, dedup (reference .set(1.0) semantics)
__global__ void sortdedup_kernel(const int* __restrict__ dptr, int* __restrict__ dtmp,
                                 int* __restrict__ dcnt) {
    int d = blockIdx.x * 256 + threadIdx.x;
    if (d >= NDRUG) return;
    int beg = dptr[d], end = dptr[d + 1];
    for (int i = beg + 1; i < end; ++i) {
        int v = dtmp[i];
        int j = i - 1;
        while (j >= beg && dtmp[j] > v) { dtmp[j + 1] = dtmp[j]; --j; }
        dtmp[j + 1] = v;
    }
    int c = 0, prev = -1;
    for (int i = beg; i < end; ++i) {
        int v = dtmp[i];
        if (v != prev) { dtmp[beg + c] = v; ++c; prev = v; }
    }
    dcnt[d] = c;
}

// per-wave stream lengths (max over 64 lanes of per-thread entry count) + bases
__global__ __launch_bounds__(512) void stream_meta_kernel(const int* __restrict__ dcnt,
                                                          int* __restrict__ wlen,
                                                          int* __restrict__ wbase) {
    __shared__ int wl[8];
    int t = threadIdx.x;
    if (t < 8) wl[t] = 0;
    __syncthreads();
    int c = 0;
    for (int k = 0; k < 8; ++k) {
        int d = t + (k << 9);
        if (d < NDRUG) c += max(dcnt[d], 1);  // empty drug still emits one dummy-last
    }
    atomicMax(&wl[t >> 6], c);
    __syncthreads();
    if (t == 0) {
        int run = 0;
        for (int w = 0; w < 8; ++w) {
            wlen[w] = wl[w];
            wbase[w] = run;
            run += wl[w] * 64;
        }
    }
}

// build wave-interleaved u16 stream: entry = p | (last<<15); lane l's i-th
// entry at wbase[wave] + i*64 + l  -> wave reads are 128B coalesced.
// Padding entries point at wst[19000] (=0). Empty drugs emit dummy-last.
__global__ __launch_bounds__(512) void fill_stream_kernel(const int* __restrict__ dptr,
                                                          const int* __restrict__ dcnt,
                                                          const int* __restrict__ dtmp,
                                                          const int* __restrict__ wbase,
                                                          const int* __restrict__ wlen,
                                                          unsigned short* __restrict__ estream) {
    int t = threadIdx.x;
    int base = wbase[t >> 6] + (t & 63);
    int idx = 0;
    for (int k = 0; k < 8; ++k) {
        int d = t + (k << 9);
        if (d >= NDRUG) continue;
        int n = dcnt[d], b = dptr[d];
        if (n == 0) {
            estream[base + (idx++) * 64] = (unsigned short)(19000 | 0x8000);
        } else {
            for (int i = 0; i < n; ++i) {
                unsigned short e = (unsigned short)dtmp[b + i];
                if (i == n - 1) e |= 0x8000;
                estream[base + (idx++) * 64] = e;
            }
        }
    }
    int wl = wlen[t >> 6];
    for (; idx < wl; ++idx) estream[base + idx * 64] = (unsigned short)19000;
}

// BASE[c][ch] = b0[ch] + W0[ch, 19000+c] + W0[ch, 38016+c]
__global__ void base_kernel(const float* __restrict__ W0, const float* __restrict__ b0,
                            float* __restrict__ BASE) {
    int i = blockIdx.x * 256 + threadIdx.x;
    if (i < NCELL * L0) {
        int c = i >> 11, ch = i & 2047;
        const float* wr = W0 + (size_t)ch * INDIM;
        BASE[(size_t)c * L0 + ch] = b0[ch] + wr[NPROT + c] + wr[HALFDIM + NPROT + c];
    }
}

// Register-accumulator drug sum. Block = one (channel, half); the full 19000-
// float W0 half-row lives in LDS (76KB, 2 blocks/CU). Thread owns drugs
// d = t + k*512, walks its wave-interleaved stream with uniform trip count:
// x += wst[p]; on 'last' a predicated store writes SA/SB[d][ch]. No LDS RMW,
// no chunks, one barrier. Grid mapped so the 16 blocks sharing each 64B
// output line are consecutive on one XCD (L2 write-merging).
__global__ __launch_bounds__(512) void drug_sum_kernel(const float* __restrict__ W0,
                                                       const unsigned short* __restrict__ estream,
                                                       const int* __restrict__ wbase,
                                                       const int* __restrict__ wlen,
                                                       float* __restrict__ SA,
                                                       float* __restrict__ SB) {
    __shared__ float wst[WSTN];  // 76032 B
    int t = threadIdx.x;
    int bid = blockIdx.x;
    // bid -> (xcd j, ch_lo, ghi): 16 blocks of a line-group share j (same XCD)
    int j = bid & 7;
    int k2 = bid >> 3;
    int ch_lo = k2 & 15;
    int ghi = k2 >> 4;               // 0..31
    int group = j + 8 * ghi;         // 0..255
    int hb = group >> 7;
    int ch = (group & 127) * 16 + ch_lo;
    size_t colbase = (size_t)hb * HALFDIM;
    const float* src = W0 + (size_t)ch * INDIM + colbase;
    for (int i = t; i < 4750; i += 512) {   // 4750 * 16B = 19000 floats
        __builtin_amdgcn_global_load_lds(
            (const __attribute__((address_space(1))) void*)(src + i * 4),
            (__attribute__((address_space(3))) void*)(&wst[i * 4]), 16, 0, 0);
    }
    if (t < 8) wst[19000 + t] = 0.f;  // dummy slot (disjoint from DMA range)
    int wv = t >> 6;
    int base = wbase[wv] + (t & 63);
    int wl = wlen[wv];
    __syncthreads();

    float x = 0.f;
    int kk = 0;
    float* dst = hb ? SB : SA;
    int i = 0;
    for (; i + 4 <= wl; i += 4) {
        unsigned e0 = estream[base];
        unsigned e1 = estream[base + 64];
        unsigned e2 = estream[base + 128];
        unsigned e3 = estream[base + 192];
        base += 256;
        float w0v = wst[e0 & 0x7fff];
        float w1v = wst[e1 & 0x7fff];
        float w2v = wst[e2 & 0x7fff];
        float w3v = wst[e3 & 0x7fff];
        x += w0v;
        if (e0 & 0x8000) { dst[(size_t)(t + (kk << 9)) * L0 + ch] = x; ++kk; x = 0.f; }
        x += w1v;
        if (e1 & 0x8000) { dst[(size_t)(t + (kk << 9)) * L0 + ch] = x; ++kk; x = 0.f; }
        x += w2v;
        if (e2 & 0x8000) { dst[(size_t)(t + (kk << 9)) * L0 + ch] = x; ++kk; x = 0.f; }
        x += w3v;
        if (e3 & 0x8000) { dst[(size_t)(t + (kk << 9)) * L0 + ch] = x; ++kk; x = 0.f; }
    }
    for (; i < wl; ++i) {
        unsigned e0 = estream[base];
        base += 64;
        x += wst[e0 & 0x7fff];
        if (e0 & 0x8000) { dst[(size_t)(t + (kk << 9)) * L0 + ch] = x; ++kk; x = 0.f; }
    }
}

__global__ void cvtw1_kernel(const float* __restrict__ W1, __hip_bfloat16* __restrict__ W1b) {
    int i = blockIdx.x * 256 + threadIdx.x;  // one float4 each
    const int n = L1DIM * L0 / 4;
    if (i < n) {
        float4 v = ((const float4*)W1)[i];
        union { ushort4 u; __hip_bfloat16 h[4]; } pk;
        pk.h[0] = __float2bfloat16(v.x);
        pk.h[1] = __float2bfloat16(v.y);
        pk.h[2] = __float2bfloat16(v.z);
        pk.h[3] = __float2bfloat16(v.w);
        ((ushort4*)W1b)[i] = pk.u;
    }
}

// h1[b]      = relu(BASE[c] + SA[d1] + SB[d2])  (x1)
// h1[4096+b] = relu(BASE[c] + SA[d2] + SB[d1])  (x2)
__global__ __launch_bounds__(256) void build_h_kernel(const int* __restrict__ dp,
                                                      const int* __restrict__ cl,
                                                      const float* __restrict__ SA,
                                                      const float* __restrict__ SB,
                                                      const float* __restrict__ BASE,
                                                      __hip_bfloat16* __restrict__ h1) {
    int b = blockIdx.x;
    int d1 = dp[2 * b], d2 = dp[2 * b + 1], c = cl[b];
    const float* bs = BASE + (size_t)c * L0;
    const float* a1 = SA + (size_t)d1 * L0;
    const float* a2 = SA + (size_t)d2 * L0;
    const float* s1 = SB + (size_t)d1 * L0;
    const float* s2 = SB + (size_t)d2 * L0;
    for (int ch = threadIdx.x * 4; ch < L0; ch += 1024) {
        float4 vb = *(const float4*)(bs + ch);
        float4 va1 = *(const float4*)(a1 + ch);
        float4 va2 = *(const float4*)(a2 + ch);
        float4 vs1 = *(const float4*)(s1 + ch);
        float4 vs2 = *(const float4*)(s2 + ch);
        union { ushort4 u; __hip_bfloat16 h[4]; } p1, p2;
        const float* fb = (const float*)&vb;
        const float* fa1 = (const float*)&va1;
        const float* fa2 = (const float*)&va2;
        const float* fs1 = (const float*)&vs1;
        const float* fs2 = (const float*)&vs2;
#pragma unroll
        for (int j = 0; j < 4; ++j) {
            float z1 = fb[j] + fa1[j] + fs2[j];
            float z2 = fb[j] + fa2[j] + fs1[j];
            p1.h[j] = __float2bfloat16(fmaxf(z1, 0.f));
            p2.h[j] = __float2bfloat16(fmaxf(z2, 0.f));
        }
        *(ushort4*)((__hip_bfloat16*)h1 + (size_t)b * L0 + ch) = p1.u;
        *(ushort4*)((__hip_bfloat16*)h1 + (size_t)(BATCH + b) * L0 + ch) = p2.u;
    }
}

// C = relu(A @ B^T + bias), A: MxK bf16, B: NxK bf16 (W1), C: MxN bf16
#define BM 128
#define BN 128
#define BKK 32
__global__ __launch_bounds__(256) void gemm_kernel(const __hip_bfloat16* __restrict__ A,
                                                   const __hip_bfloat16* __restrict__ B,
                                                   const float* __restrict__ bias,
                                                   __hip_bfloat16* __restrict__ C,
                                                   int M, int N, int K) {
    __shared__ __hip_bfloat16 As[BM * BKK];
    __shared__ __hip_bfloat16 Bs[BN * BKK];
    int t = threadIdx.x;
    int ntiles = N / BN;
    int bx = blockIdx.x % ntiles;
    int by = blockIdx.x / ntiles;
    int brow = by * BM, bcol = bx * BN;
    int w = t >> 6, l = t & 63;
    int wr = w >> 1, wc = w & 1;
    f32x4 acc[4][4] = {};
    int row = l & 15, ko = (l >> 4) * 8;
    for (int k0 = 0; k0 < K; k0 += BKK) {
#pragma unroll
        for (int i = 0; i < 2; ++i) {
            int idx = i * 256 + t;
            int r = idx >> 2, cb = (idx & 3) * 8;
            __builtin_amdgcn_global_load_lds(
                (const __attribute__((address_space(1))) void*)(A + (size_t)(brow + r) * K + k0 + cb),
                (__attribute__((address_space(3))) void*)(&As[idx * 8]), 16, 0, 0);
            __builtin_amdgcn_global_load_lds(
                (const __attribute__((address_space(1))) void*)(B + (size_t)(bcol + r) * K + k0 + cb),
                (__attribute__((address_space(3))) void*)(&Bs[idx * 8]), 16, 0, 0);
        }
        __syncthreads();
        s16x8 af[4], bfr[4];
#pragma unroll
        for (int m = 0; m < 4; ++m)
            af[m] = *(const s16x8*)(&As[(wr * 64 + m * 16 + row) * BKK + ko]);
#pragma unroll
        for (int n = 0; n < 4; ++n)
            bfr[n] = *(const s16x8*)(&Bs[(wc * 64 + n * 16 + row) * BKK + ko]);
#pragma unroll
        for (int m = 0; m < 4; ++m)
#pragma unroll
            for (int n = 0; n < 4; ++n)
                acc[m][n] = __builtin_amdgcn_mfma_f32_16x16x32_bf16(af[m], bfr[n], acc[m][n], 0, 0, 0);
        __syncthreads();
    }
    int cr = (l >> 4) * 4;
    int cc = l & 15;
#pragma unroll
    for (int m = 0; m < 4; ++m)
#pragma unroll
        for (int n = 0; n < 4; ++n) {
#pragma unroll
            for (int j = 0; j < 4; ++j) {
                int grow = brow + wr * 64 + m * 16 + cr + j;
                int gcol = bcol + wc * 64 + n * 16 + cc;
                float v = acc[m][n][j] + bias[gcol];
                C[(size_t)grow * N + gcol] = __float2bfloat16(fmaxf(v, 0.f));
            }
        }
}

// out[r] = b2 + sum_o h2[r][o] * W2[o]
__global__ __launch_bounds__(128) void out_kernel(const __hip_bfloat16* __restrict__ h2,
                                                  const float* __restrict__ W2,
                                                  const float* __restrict__ b2,
                                                  float* __restrict__ out) {
    int r = blockIdx.x;
    int t = threadIdx.x;
    union { uint4 u; __hip_bfloat16 h[8]; } pk;
    pk.u = *(const uint4*)(h2 + (size_t)r * L1DIM + t * 8);
    float s = 0.f;
#pragma unroll
    for (int j = 0; j < 8; ++j) s += __bfloat162float(pk.h[j]) * W2[t * 8 + j];
    for (int o = 32; o > 0; o >>= 1) s += __shfl_down(s, o);
    __shared__ float red[2];
    if ((t & 63) == 0) red[t >> 6] = s;
    __syncthreads();
    if (t == 0) out[r] = red[0] + red[1] + b2[0];
}

extern "C" void kernel_launch(void* const* d_in, const int* in_sizes, int n_in,
                              void* d_out, int out_size, void* d_ws, size_t ws_size,
                              hipStream_t stream) {
    const int* drug_pairs = (const int*)d_in[0];
    const int* cell_lines = (const int*)d_in[1];
    const int* dpi_drug = (const int*)d_in[2];
    const int* dpi_prot = (const int*)d_in[3];
    const float* W0 = (const float*)d_in[4];
    const float* b0 = (const float*)d_in[5];
    const float* W1 = (const float*)d_in[6];
    const float* b1 = (const float*)d_in[7];
    const float* W2 = (const float*)d_in[8];
    const float* b2 = (const float*)d_in[9];
    float* out = (float*)d_out;

    char* ws = (char*)d_ws;
    size_t off = 0;
    auto alloc = [&](size_t bytes) {
        char* p = ws + off;
        off += (bytes + 255) & ~(size_t)255;
        return p;
    };
    float* SA = (float*)alloc((size_t)NDRUG * L0 * 4);
    float* SB = (float*)alloc((size_t)NDRUG * L0 * 4);
    float* BASE = (float*)alloc((size_t)NCELL * L0 * 4);
    __hip_bfloat16* W1b = (__hip_bfloat16*)alloc((size_t)L1DIM * L0 * 2);
    __hip_bfloat16* h1 = (__hip_bfloat16*)alloc((size_t)2 * BATCH * L0 * 2);
    __hip_bfloat16* h2 = (__hip_bfloat16*)alloc((size_t)2 * BATCH * L1DIM * 2);
    // contiguous zero region: hist, cnt
    const int ZREG_N = 2 * NDRUG;
    int* zreg = (int*)alloc((size_t)ZREG_N * 4);
    int* hist = zreg;
    int* cnt = zreg + NDRUG;
    int* dptr = (int*)alloc((size_t)(NDRUG + 1) * 4);
    int* dtmp = (int*)alloc((size_t)NEDGE * 4);
    int* dcnt = (int*)alloc((size_t)NDRUG * 4);
    int* wlen = (int*)alloc(8 * 4);
    int* wbase = (int*)alloc(8 * 4);
    // worst-case stream: 64 lanes * (all edges + dummies on one thread)
    unsigned short* estream = (unsigned short*)alloc((size_t)64 * (NEDGE + NDRUG + 512) * 2);

    zero_all_kernel<<<(ZREG_N + 255) / 256, 256, 0, stream>>>(zreg, ZREG_N);
    hist_kernel<<<(NEDGE + 255) / 256, 256, 0, stream>>>(dpi_drug, hist);
    scan_kernel<<<1, 256, 0, stream>>>(hist, dptr, NDRUG);
    scatter_kernel<<<(NEDGE + 255) / 256, 256, 0, stream>>>(dpi_drug, dpi_prot, dptr, cnt, dtmp);
    sortdedup_kernel<<<(NDRUG + 255) / 256, 256, 0, stream>>>(dptr, dtmp, dcnt);
    stream_meta_kernel<<<1, 512, 0, stream>>>(dcnt, wlen, wbase);
    fill_stream_kernel<<<1, 512, 0, stream>>>(dptr, dcnt, dtmp, wbase, wlen, estream);
    base_kernel<<<(NCELL * L0 + 255) / 256, 256, 0, stream>>>(W0, b0, BASE);
    drug_sum_kernel<<<2 * L0, 512, 0, stream>>>(W0, estream, wbase, wlen, SA, SB);
    cvtw1_kernel<<<(L1DIM * L0 / 4 + 255) / 256, 256, 0, stream>>>(W1, W1b);
    build_h_kernel<<<BATCH, 256, 0, stream>>>(drug_pairs, cell_lines, SA, SB, BASE, h1);
    gemm_kernel<<<(2 * BATCH / BM) * (L1DIM / BN), 256, 0, stream>>>(h1, W1b, b1, h2,
                                                                     2 * BATCH, L1DIM, L0);
    out_kernel<<<2 * BATCH, 128, 0, stream>>>(h2, W2, b2, out);
}

// Round 8
// 334.445 us; speedup vs baseline: 3.6273x; 1.1053x over previous
//
#include <hip/hip_runtime.h>
#include <hip/hip_bf16.h>
#include <stdint.h>

#define NPROT 19000
#define NDRUG 4000
#define NCELL 16
#define BATCH 4096
#define NEDGE 40000
#define L0 2048
#define L1DIM 1024
#define INDIM 38032
#define HALFDIM 19016
#define WSTN 19008   // dwords: 19000 + 8 pad (dummy slot at 19000)

typedef float f32x4 __attribute__((ext_vector_type(4)));
typedef short s16x8 __attribute__((ext_vector_type(8)));

__global__ void zero_all_kernel(int* __restrict__ p, int n) {
    int i = blockIdx.x * 256 + threadIdx.x;
    if (i < n) p[i] = 0;
}

__global__ void hist_kernel(const int* __restrict__ drug, int* __restrict__ hist) {
    int e = blockIdx.x * 256 + threadIdx.x;
    if (e < NEDGE) atomicAdd(&hist[drug[e]], 1);
}

// generic single-block exclusive scan: row_ptr[0..n], row_ptr[n] = total
__global__ __launch_bounds__(256) void scan_kernel(const int* __restrict__ hist,
                                                   int* __restrict__ row_ptr, int n) {
    __shared__ int part[256];
    int t = threadIdx.x;
    int per = (n + 255) / 256;
    int s = 0;
    for (int j = 0; j < per; ++j) {
        int idx = t * per + j;
        if (idx < n) s += hist[idx];
    }
    part[t] = s;
    __syncthreads();
    if (t == 0) {
        int run = 0;
        for (int i = 0; i < 256; ++i) { int v = part[i]; part[i] = run; run += v; }
    }
    __syncthreads();
    int run = part[t];
    for (int j = 0; j < per; ++j) {
        int idx = t * per + j;
        if (idx < n) { row_ptr[idx] = run; run += hist[idx]; }
    }
    if (t == 255) row_ptr[n] = run;
}

// CSR by drug: dtmp[dptr[d] + k] = protein
__global__ void scatter_kernel(const int* __restrict__ drug, const int* __restrict__ prot,
                               const int* __restrict__ dptr, int* __restrict__ cnt,
                               int* __restrict__ dtmp) {
    int e = blockIdx.x * 256 + threadIdx.x;
    if (e < NEDGE) {
        int d = drug[e];
        int pos = dptr[d] + atomicAdd(&cnt[d], 1);
        dtmp[pos] = prot[e];
    }
}

// per-drug: insertion-sort protein list, dedup (reference .set(1.0) semantics)
__global__ void sortdedup_kernel(const int* __restrict__ dptr, int* __restrict__ dtmp,
                                 int* __restrict__ dcnt) {
    int d = blockIdx.x * 256 + threadIdx.x;
    if (d >= NDRUG) return;
    int beg = dptr[d], end = dptr[d + 1];
    for (int i = beg + 1; i < end; ++i) {
        int v = dtmp[i];
        int j = i - 1;
        while (j >= beg && dtmp[j] > v) { dtmp[j + 1] = dtmp[j]; --j; }
        dtmp[j + 1] = v;
    }
    int c = 0, prev = -1;
    for (int i = beg; i < end; ++i) {
        int v = dtmp[i];
        if (v != prev) { dtmp[beg + c] = v; ++c; prev = v; }
    }
    dcnt[d] = c;
}

// fused: per-wave stream lengths/bases, then fill wave-interleaved u16 stream
// entry = p | (last<<15); lane l's i-th entry at wbase[wave] + i*64 + l.
// Padding entries point at wst[19000] (=0). Empty drugs emit dummy-last.
__global__ __launch_bounds__(512) void stream_build_kernel(const int* __restrict__ dptr,
                                                           const int* __restrict__ dcnt,
                                                           const int* __restrict__ dtmp,
                                                           int* __restrict__ wlen,
                                                           int* __restrict__ wbase,
                                                           unsigned short* __restrict__ estream) {
    __shared__ int wl[8];
    __shared__ int wb[8];
    int t = threadIdx.x;
    if (t < 8) wl[t] = 0;
    __syncthreads();
    int c = 0;
    for (int k = 0; k < 8; ++k) {
        int d = t + (k << 9);
        if (d < NDRUG) c += max(dcnt[d], 1);
    }
    atomicMax(&wl[t >> 6], c);
    __syncthreads();
    if (t == 0) {
        int run = 0;
        for (int w = 0; w < 8; ++w) {
            wlen[w] = wl[w];
            wb[w] = run;
            wbase[w] = run;
            run += wl[w] * 64;
        }
    }
    __syncthreads();
    int base = wb[t >> 6] + (t & 63);
    int idx = 0;
    for (int k = 0; k < 8; ++k) {
        int d = t + (k << 9);
        if (d >= NDRUG) continue;
        int n = dcnt[d], b = dptr[d];
        if (n == 0) {
            estream[base + (idx++) * 64] = (unsigned short)(19000 | 0x8000);
        } else {
            for (int i = 0; i < n; ++i) {
                unsigned short e = (unsigned short)dtmp[b + i];
                if (i == n - 1) e |= 0x8000;
                estream[base + (idx++) * 64] = e;
            }
        }
    }
    int mywl = wl[t >> 6];
    for (; idx < mywl; ++idx) estream[base + idx * 64] = (unsigned short)19000;
}

// BASE[c][ch] = b0[ch] + W0[ch, 19000+c] + W0[ch, 38016+c]
__global__ void base_kernel(const float* __restrict__ W0, const float* __restrict__ b0,
                            float* __restrict__ BASE) {
    int i = blockIdx.x * 256 + threadIdx.x;
    if (i < NCELL * L0) {
        int c = i >> 11, ch = i & 2047;
        const float* wr = W0 + (size_t)ch * INDIM;
        BASE[(size_t)c * L0 + ch] = b0[ch] + wr[NPROT + c] + wr[HALFDIM + NPROT + c];
    }
}

// RNE f32->bf16 pair pack: low16 = a, high16 = b
__device__ inline unsigned bfpair(float a, float b) {
    unsigned ua = __float_as_uint(a), ub = __float_as_uint(b);
    ua += 0x7fffu + ((ua >> 16) & 1u);
    ub += 0x7fffu + ((ub >> 16) & 1u);
    return (ua >> 16) | (ub & 0xffff0000u);
}

// Register-accumulator drug sum, 2 channels/block as packed bf16 in LDS.
// Block = (channel-pair, half); wst[p] = bf16(W0[ch0][p]) | bf16(W0[ch0+1][p])<<16
// (76KB LDS, 2 blocks/CU). Thread owns drugs d = t + k*512; walks its
// wave-interleaved stream (uniform trip count, batch-8 software pipeline):
// x += unpack(wst[p]); on 'last' a predicated float2 store writes SA/SB[d][ch0..1].
__global__ __launch_bounds__(512) void drug_sum_kernel(const float* __restrict__ W0,
                                                       const unsigned short* __restrict__ estream,
                                                       const int* __restrict__ wbase,
                                                       const int* __restrict__ wlen,
                                                       float* __restrict__ SA,
                                                       float* __restrict__ SB) {
    __shared__ unsigned wst[WSTN];  // 76032 B
    int t = threadIdx.x;
    int bid = blockIdx.x;           // 2048 blocks
    // 8 blocks covering one 64B output line share bid&7 (same XCD heuristic)
    int j = bid & 7;
    int k2 = bid >> 3;
    int ch8 = k2 & 7;
    int ghi = k2 >> 3;               // 0..31
    int group = j + 8 * ghi;         // 0..255
    int hb = group >> 7;
    int chpair = (group & 127) * 8 + ch8;   // 0..1023
    int ch0 = chpair * 2;
    size_t colbase = (size_t)hb * HALFDIM;

    const float* srcA = W0 + (size_t)ch0 * INDIM + colbase;
    const float* srcB = W0 + (size_t)(ch0 + 1) * INDIM + colbase;
    for (int i = t * 4; i < 19000; i += 2048) {
        float4 a = *(const float4*)(srcA + i);
        float4 b = *(const float4*)(srcB + i);
        uint4 q;
        q.x = bfpair(a.x, b.x);
        q.y = bfpair(a.y, b.y);
        q.z = bfpair(a.z, b.z);
        q.w = bfpair(a.w, b.w);
        *(uint4*)&wst[i] = q;
    }
    if (t < 8) wst[19000 + t] = 0u;  // dummy slot
    int wv = t >> 6;
    int base = wbase[wv] + (t & 63);
    int wl = wlen[wv];
    __syncthreads();

    float x0 = 0.f, x1 = 0.f;
    int kk = 0;
    float* dst = (hb ? SB : SA) + ch0;

    int nfull = wl >> 3, rem = wl & 7;
    unsigned e[8];

    auto process = [&](const unsigned* ev) {
#pragma unroll
        for (int k = 0; k < 8; ++k) {
            unsigned w = wst[ev[k] & 0x7fffu];
            x0 += __uint_as_float(w << 16);
            x1 += __uint_as_float(w & 0xffff0000u);
            if (ev[k] & 0x8000u) {
                float2 v;
                v.x = x0; v.y = x1;
                *(float2*)&dst[(size_t)(t + (kk << 9)) * L0] = v;
                ++kk; x0 = 0.f; x1 = 0.f;
            }
        }
    };

    if (nfull > 0) {
#pragma unroll
        for (int k = 0; k < 8; ++k) e[k] = estream[base + k * 64];
        base += 512;
        for (int it = 1; it < nfull; ++it) {
            unsigned f[8];
#pragma unroll
            for (int k = 0; k < 8; ++k) f[k] = estream[base + k * 64];
            base += 512;
            process(e);
#pragma unroll
            for (int k = 0; k < 8; ++k) e[k] = f[k];
        }
        process(e);
    }
    for (int k = 0; k < rem; ++k) {
        unsigned ev = estream[base + k * 64];
        unsigned w = wst[ev & 0x7fffu];
        x0 += __uint_as_float(w << 16);
        x1 += __uint_as_float(w & 0xffff0000u);
        if (ev & 0x8000u) {
            float2 v;
            v.x = x0; v.y = x1;
            *(float2*)&dst[(size_t)(t + (kk << 9)) * L0] = v;
            ++kk; x0 = 0.f; x1 = 0.f;
        }
    }
}

__global__ void cvtw1_kernel(const float* __restrict__ W1, __hip_bfloat16* __restrict__ W1b) {
    int i = blockIdx.x * 256 + threadIdx.x;  // one float4 each
    const int n = L1DIM * L0 / 4;
    if (i < n) {
        float4 v = ((const float4*)W1)[i];
        union { ushort4 u; __hip_bfloat16 h[4]; } pk;
        pk.h[0] = __float2bfloat16(v.x);
        pk.h[1] = __float2bfloat16(v.y);
        pk.h[2] = __float2bfloat16(v.z);
        pk.h[3] = __float2bfloat16(v.w);
        ((ushort4*)W1b)[i] = pk.u;
    }
}

// h1[b]      = relu(BASE[c] + SA[d1] + SB[d2])  (x1)
// h1[4096+b] = relu(BASE[c] + SA[d2] + SB[d1])  (x2)
__global__ __launch_bounds__(256) void build_h_kernel(const int* __restrict__ dp,
                                                      const int* __restrict__ cl,
                                                      const float* __restrict__ SA,
                                                      const float* __restrict__ SB,
                                                      const float* __restrict__ BASE,
                                                      __hip_bfloat16* __restrict__ h1) {
    int b = blockIdx.x;
    int d1 = dp[2 * b], d2 = dp[2 * b + 1], c = cl[b];
    const float* bs = BASE + (size_t)c * L0;
    const float* a1 = SA + (size_t)d1 * L0;
    const float* a2 = SA + (size_t)d2 * L0;
    const float* s1 = SB + (size_t)d1 * L0;
    const float* s2 = SB + (size_t)d2 * L0;
    for (int ch = threadIdx.x * 4; ch < L0; ch += 1024) {
        float4 vb = *(const float4*)(bs + ch);
        float4 va1 = *(const float4*)(a1 + ch);
        float4 va2 = *(const float4*)(a2 + ch);
        float4 vs1 = *(const float4*)(s1 + ch);
        float4 vs2 = *(const float4*)(s2 + ch);
        union { ushort4 u; __hip_bfloat16 h[4]; } p1, p2;
        const float* fb = (const float*)&vb;
        const float* fa1 = (const float*)&va1;
        const float* fa2 = (const float*)&va2;
        const float* fs1 = (const float*)&vs1;
        const float* fs2 = (const float*)&vs2;
#pragma unroll
        for (int j = 0; j < 4; ++j) {
            float z1 = fb[j] + fa1[j] + fs2[j];
            float z2 = fb[j] + fa2[j] + fs1[j];
            p1.h[j] = __float2bfloat16(fmaxf(z1, 0.f));
            p2.h[j] = __float2bfloat16(fmaxf(z2, 0.f));
        }
        *(ushort4*)((__hip_bfloat16*)h1 + (size_t)b * L0 + ch) = p1.u;
        *(ushort4*)((__hip_bfloat16*)h1 + (size_t)(BATCH + b) * L0 + ch) = p2.u;
    }
}

// C = relu(A @ B^T + bias), A: MxK bf16, B: NxK bf16 (W1), C: MxN bf16
#define BM 128
#define BN 128
#define BKK 32
__global__ __launch_bounds__(256) void gemm_kernel(const __hip_bfloat16* __restrict__ A,
                                                   const __hip_bfloat16* __restrict__ B,
                                                   const float* __restrict__ bias,
                                                   __hip_bfloat16* __restrict__ C,
                                                   int M, int N, int K) {
    __shared__ __hip_bfloat16 As[BM * BKK];
    __shared__ __hip_bfloat16 Bs[BN * BKK];
    int t = threadIdx.x;
    int ntiles = N / BN;
    int bx = blockIdx.x % ntiles;
    int by = blockIdx.x / ntiles;
    int brow = by * BM, bcol = bx * BN;
    int w = t >> 6, l = t & 63;
    int wr = w >> 1, wc = w & 1;
    f32x4 acc[4][4] = {};
    int row = l & 15, ko = (l >> 4) * 8;
    for (int k0 = 0; k0 < K; k0 += BKK) {
#pragma unroll
        for (int i = 0; i < 2; ++i) {
            int idx = i * 256 + t;
            int r = idx >> 2, cb = (idx & 3) * 8;
            __builtin_amdgcn_global_load_lds(
                (const __attribute__((address_space(1))) void*)(A + (size_t)(brow + r) * K + k0 + cb),
                (__attribute__((address_space(3))) void*)(&As[idx * 8]), 16, 0, 0);
            __builtin_amdgcn_global_load_lds(
                (const __attribute__((address_space(1))) void*)(B + (size_t)(bcol + r) * K + k0 + cb),
                (__attribute__((address_space(3))) void*)(&Bs[idx * 8]), 16, 0, 0);
        }
        __syncthreads();
        s16x8 af[4], bfr[4];
#pragma unroll
        for (int m = 0; m < 4; ++m)
            af[m] = *(const s16x8*)(&As[(wr * 64 + m * 16 + row) * BKK + ko]);
#pragma unroll
        for (int n = 0; n < 4; ++n)
            bfr[n] = *(const s16x8*)(&Bs[(wc * 64 + n * 16 + row) * BKK + ko]);
#pragma unroll
        for (int m = 0; m < 4; ++m)
#pragma unroll
            for (int n = 0; n < 4; ++n)
                acc[m][n] = __builtin_amdgcn_mfma_f32_16x16x32_bf16(af[m], bfr[n], acc[m][n], 0, 0, 0);
        __syncthreads();
    }
    int cr = (l >> 4) * 4;
    int cc = l & 15;
#pragma unroll
    for (int m = 0; m < 4; ++m)
#pragma unroll
        for (int n = 0; n < 4; ++n) {
#pragma unroll
            for (int j = 0; j < 4; ++j) {
                int grow = brow + wr * 64 + m * 16 + cr + j;
                int gcol = bcol + wc * 64 + n * 16 + cc;
                float v = acc[m][n][j] + bias[gcol];
                C[(size_t)grow * N + gcol] = __float2bfloat16(fmaxf(v, 0.f));
            }
        }
}

// out[r] = b2 + sum_o h2[r][o] * W2[o]
__global__ __launch_bounds__(128) void out_kernel(const __hip_bfloat16* __restrict__ h2,
                                                  const float* __restrict__ W2,
                                                  const float* __restrict__ b2,
                                                  float* __restrict__ out) {
    int r = blockIdx.x;
    int t = threadIdx.x;
    union { uint4 u; __hip_bfloat16 h[8]; } pk;
    pk.u = *(const uint4*)(h2 + (size_t)r * L1DIM + t * 8);
    float s = 0.f;
#pragma unroll
    for (int j = 0; j < 8; ++j) s += __bfloat162float(pk.h[j]) * W2[t * 8 + j];
    for (int o = 32; o > 0; o >>= 1) s += __shfl_down(s, o);
    __shared__ float red[2];
    if ((t & 63) == 0) red[t >> 6] = s;
    __syncthreads();
    if (t == 0) out[r] = red[0] + red[1] + b2[0];
}

extern "C" void kernel_launch(void* const* d_in, const int* in_sizes, int n_in,
                              void* d_out, int out_size, void* d_ws, size_t ws_size,
                              hipStream_t stream) {
    const int* drug_pairs = (const int*)d_in[0];
    const int* cell_lines = (const int*)d_in[1];
    const int* dpi_drug = (const int*)d_in[2];
    const int* dpi_prot = (const int*)d_in[3];
    const float* W0 = (const float*)d_in[4];
    const float* b0 = (const float*)d_in[5];
    const float* W1 = (const float*)d_in[6];
    const float* b1 = (const float*)d_in[7];
    const float* W2 = (const float*)d_in[8];
    const float* b2 = (const float*)d_in[9];
    float* out = (float*)d_out;

    char* ws = (char*)d_ws;
    size_t off = 0;
    auto alloc = [&](size_t bytes) {
        char* p = ws + off;
        off += (bytes + 255) & ~(size_t)255;
        return p;
    };
    float* SA = (float*)alloc((size_t)NDRUG * L0 * 4);
    float* SB = (float*)alloc((size_t)NDRUG * L0 * 4);
    float* BASE = (float*)alloc((size_t)NCELL * L0 * 4);
    __hip_bfloat16* W1b = (__hip_bfloat16*)alloc((size_t)L1DIM * L0 * 2);
    __hip_bfloat16* h1 = (__hip_bfloat16*)alloc((size_t)2 * BATCH * L0 * 2);
    __hip_bfloat16* h2 = (__hip_bfloat16*)alloc((size_t)2 * BATCH * L1DIM * 2);
    // contiguous zero region: hist, cnt
    const int ZREG_N = 2 * NDRUG;
    int* zreg = (int*)alloc((size_t)ZREG_N * 4);
    int* hist = zreg;
    int* cnt = zreg + NDRUG;
    int* dptr = (int*)alloc((size_t)(NDRUG + 1) * 4);
    int* dtmp = (int*)alloc((size_t)NEDGE * 4);
    int* dcnt = (int*)alloc((size_t)NDRUG * 4);
    int* wlen = (int*)alloc(8 * 4);
    int* wbase = (int*)alloc(8 * 4);
    unsigned short* estream = (unsigned short*)alloc((size_t)64 * (NEDGE + NDRUG + 512) * 2);

    zero_all_kernel<<<(ZREG_N + 255) / 256, 256, 0, stream>>>(zreg, ZREG_N);
    hist_kernel<<<(NEDGE + 255) / 256, 256, 0, stream>>>(dpi_drug, hist);
    scan_kernel<<<1, 256, 0, stream>>>(hist, dptr, NDRUG);
    scatter_kernel<<<(NEDGE + 255) / 256, 256, 0, stream>>>(dpi_drug, dpi_prot, dptr, cnt, dtmp);
    sortdedup_kernel<<<(NDRUG + 255) / 256, 256, 0, stream>>>(dptr, dtmp, dcnt);
    stream_build_kernel<<<1, 512, 0, stream>>>(dptr, dcnt, dtmp, wlen, wbase, estream);
    base_kernel<<<(NCELL * L0 + 255) / 256, 256, 0, stream>>>(W0, b0, BASE);
    drug_sum_kernel<<<L0, 512, 0, stream>>>(W0, estream, wbase, wlen, SA, SB);
    cvtw1_kernel<<<(L1DIM * L0 / 4 + 255) / 256, 256, 0, stream>>>(W1, W1b);
    build_h_kernel<<<BATCH, 256, 0, stream>>>(drug_pairs, cell_lines, SA, SB, BASE, h1);
    gemm_kernel<<<(2 * BATCH / BM) * (L1DIM / BN), 256, 0, stream>>>(h1, W1b, b1, h2,
                                                                     2 * BATCH, L1DIM, L0);
    out_kernel<<<2 * BATCH, 128, 0, stream>>>(h2, W2, b2, out);
}

// Round 9
// 285.442 us; speedup vs baseline: 4.2500x; 1.1717x over previous
//
#include <hip/hip_runtime.h>
#include <hip/hip_bf16.h>
#include <stdint.h>

#define NPROT 19000
#define NDRUG 4000
#define NCELL 16
#define BATCH 4096
#define NEDGE 40000
#define L0 2048
#define L1DIM 1024
#define INDIM 38032
#define HALFDIM 19016
#define WSTN 19008   // protein slots: 19000 + 8 pad (dummy at 19000)

typedef float f32x4 __attribute__((ext_vector_type(4)));
typedef short s16x8 __attribute__((ext_vector_type(8)));

__global__ void zero_all_kernel(int* __restrict__ p, int n) {
    int i = blockIdx.x * 256 + threadIdx.x;
    if (i < n) p[i] = 0;
}

__global__ void hist_kernel(const int* __restrict__ drug, int* __restrict__ hist) {
    int e = blockIdx.x * 256 + threadIdx.x;
    if (e < NEDGE) atomicAdd(&hist[drug[e]], 1);
}

// generic single-block exclusive scan: row_ptr[0..n], row_ptr[n] = total
__global__ __launch_bounds__(256) void scan_kernel(const int* __restrict__ hist,
                                                   int* __restrict__ row_ptr, int n) {
    __shared__ int part[256];
    int t = threadIdx.x;
    int per = (n + 255) / 256;
    int s = 0;
    for (int j = 0; j < per; ++j) {
        int idx = t * per + j;
        if (idx < n) s += hist[idx];
    }
    part[t] = s;
    __syncthreads();
    if (t == 0) {
        int run = 0;
        for (int i = 0; i < 256; ++i) { int v = part[i]; part[i] = run; run += v; }
    }
    __syncthreads();
    int run = part[t];
    for (int j = 0; j < per; ++j) {
        int idx = t * per + j;
        if (idx < n) { row_ptr[idx] = run; run += hist[idx]; }
    }
    if (t == 255) row_ptr[n] = run;
}

// CSR by drug: dtmp[dptr[d] + k] = protein
__global__ void scatter_kernel(const int* __restrict__ drug, const int* __restrict__ prot,
                               const int* __restrict__ dptr, int* __restrict__ cnt,
                               int* __restrict__ dtmp) {
    int e = blockIdx.x * 256 + threadIdx.x;
    if (e < NEDGE) {
        int d = drug[e];
        int pos = dptr[d] + atomicAdd(&cnt[d], 1);
        dtmp[pos] = prot[e];
    }
}

// per-drug: insertion-sort protein list, dedup (reference .set(1.0) semantics)
__global__ void sortdedup_kernel(const int* __restrict__ dptr, int* __restrict__ dtmp,
                                 int* __restrict__ dcnt) {
    int d = blockIdx.x * 256 + threadIdx.x;
    if (d >= NDRUG) return;
    int beg = dptr[d], end = dptr[d + 1];
    for (int i = beg + 1; i < end; ++i) {
        int v = dtmp[i];
        int j = i - 1;
        while (j >= beg && dtmp[j] > v) { dtmp[j + 1] = dtmp[j]; --j; }
        dtmp[j + 1] = v;
    }
    int c = 0, prev = -1;
    for (int i = beg; i < end; ++i) {
        int v = dtmp[i];
        if (v != prev) { dtmp[beg + c] = v; ++c; prev = v; }
    }
    dcnt[d] = c;
}

// per-slot (512 threads) prefix of entry counts over the 8 owned drugs;
// wlen[w] = max over 64 lanes of total; wbase = running base
__global__ __launch_bounds__(512) void stream_meta_kernel(const int* __restrict__ dcnt,
                                                          int* __restrict__ wlen,
                                                          int* __restrict__ wbase,
                                                          int* __restrict__ pref,
                                                          int* __restrict__ tcnt) {
    __shared__ int wl[8];
    int t = threadIdx.x;
    if (t < 8) wl[t] = 0;
    __syncthreads();
    int c = 0;
#pragma unroll
    for (int k = 0; k < 8; ++k) {
        int d = t + (k << 9);
        pref[t * 8 + k] = c;
        if (d < NDRUG) c += max(dcnt[d], 1);
    }
    tcnt[t] = c;
    atomicMax(&wl[t >> 6], c);
    __syncthreads();
    if (t == 0) {
        int run = 0;
        for (int w = 0; w < 8; ++w) {
            wlen[w] = wl[w];
            wbase[w] = run;
            run += wl[w] * 64;
        }
    }
}

// drug-parallel fill of the wave-interleaved u16 stream.
// entry = p | (last<<15); slot t's i-th entry at wbase[t>>6] + (t&63) + i*64.
// Threads 0..3999: one drug each. Threads 4000..4511: padding worker for slot.
__global__ __launch_bounds__(256) void fill_stream_kernel(const int* __restrict__ dptr,
                                                          const int* __restrict__ dcnt,
                                                          const int* __restrict__ dtmp,
                                                          const int* __restrict__ wbase,
                                                          const int* __restrict__ wlen,
                                                          const int* __restrict__ pref,
                                                          const int* __restrict__ tcnt,
                                                          unsigned short* __restrict__ estream) {
    int g = blockIdx.x * 256 + threadIdx.x;
    if (g < NDRUG) {
        int d = g;
        int t = d & 511, k = d >> 9;
        int base = wbase[t >> 6] + (t & 63);
        int idx = pref[t * 8 + k];
        int n = dcnt[d], b = dptr[d];
        if (n == 0) {
            estream[base + idx * 64] = (unsigned short)(19000 | 0x8000);
        } else {
            for (int i = 0; i < n; ++i) {
                unsigned short e = (unsigned short)dtmp[b + i];
                if (i == n - 1) e |= 0x8000;
                estream[base + (idx + i) * 64] = e;
            }
        }
    } else if (g < NDRUG + 512) {
        int t = g - NDRUG;
        int base = wbase[t >> 6] + (t & 63);
        int wl = wlen[t >> 6];
        for (int idx = tcnt[t]; idx < wl; ++idx)
            estream[base + idx * 64] = (unsigned short)19000;
    }
}

// BASE[c][ch] = b0[ch] + W0[ch, 19000+c] + W0[ch, 38016+c]
__global__ void base_kernel(const float* __restrict__ W0, const float* __restrict__ b0,
                            float* __restrict__ BASE) {
    int i = blockIdx.x * 256 + threadIdx.x;
    if (i < NCELL * L0) {
        int c = i >> 11, ch = i & 2047;
        const float* wr = W0 + (size_t)ch * INDIM;
        BASE[(size_t)c * L0 + ch] = b0[ch] + wr[NPROT + c] + wr[HALFDIM + NPROT + c];
    }
}

// RNE f32->bf16 pair pack: low16 = a, high16 = b
__device__ inline unsigned bfpair(float a, float b) {
    unsigned ua = __float_as_uint(a), ub = __float_as_uint(b);
    ua += 0x7fffu + ((ua >> 16) & 1u);
    ub += 0x7fffu + ((ub >> 16) & 1u);
    return (ua >> 16) | (ub & 0xffff0000u);
}

// Register-accumulator drug sum, 4 channels/block as 2 packed-bf16 dwords.
// Block = (channel-quad, half); wst[p] = {bf16(ch0,ch1), bf16(ch2,ch3)}
// (152 KB LDS, 1 block/CU). Thread owns drugs d = t + k*512; walks its
// wave-interleaved stream (uniform trip count, batch-8 pipeline):
// one ds_read_b64 feeds 4 channel-accumulators; on 'last' one float4 store.
__global__ __launch_bounds__(512) void drug_sum_kernel(const float* __restrict__ W0,
                                                       const unsigned short* __restrict__ estream,
                                                       const int* __restrict__ wbase,
                                                       const int* __restrict__ wlen,
                                                       float* __restrict__ SA,
                                                       float* __restrict__ SB) {
    __shared__ uint2 wst[WSTN];  // 152064 B
    int t = threadIdx.x;
    int bid = blockIdx.x;        // 1024 blocks
    // 4 blocks covering one 64B output line share bid&7 (same-XCD heuristic)
    int j = bid & 7;
    int k2 = bid >> 3;           // 0..127
    int ch4 = k2 & 3;
    int ghi = k2 >> 2;           // 0..31
    int group = j + 8 * ghi;     // 0..255
    int hb = group >> 7;
    int line = group & 127;
    int ch0 = line * 16 + ch4 * 4;
    size_t colbase = (size_t)hb * HALFDIM;

    const float* sA = W0 + (size_t)(ch0 + 0) * INDIM + colbase;
    const float* sB = W0 + (size_t)(ch0 + 1) * INDIM + colbase;
    const float* sC = W0 + (size_t)(ch0 + 2) * INDIM + colbase;
    const float* sD = W0 + (size_t)(ch0 + 3) * INDIM + colbase;
    for (int i = t * 4; i < 19000; i += 2048) {
        float4 a = *(const float4*)(sA + i);
        float4 b = *(const float4*)(sB + i);
        float4 c = *(const float4*)(sC + i);
        float4 d = *(const float4*)(sD + i);
        uint4 q0, q1;
        q0.x = bfpair(a.x, b.x); q0.y = bfpair(c.x, d.x);
        q0.z = bfpair(a.y, b.y); q0.w = bfpair(c.y, d.y);
        q1.x = bfpair(a.z, b.z); q1.y = bfpair(c.z, d.z);
        q1.z = bfpair(a.w, b.w); q1.w = bfpair(c.w, d.w);
        *(uint4*)&wst[i] = q0;
        *(uint4*)&wst[i + 2] = q1;
    }
    if (t < 8) { wst[19000 + t].x = 0u; wst[19000 + t].y = 0u; }
    int wv = t >> 6;
    int base = wbase[wv] + (t & 63);
    int wl = wlen[wv];
    __syncthreads();

    float x0 = 0.f, x1 = 0.f, x2 = 0.f, x3 = 0.f;
    int kk = 0;
    float* dst = (hb ? SB : SA) + ch0;

    int nfull = wl >> 3, rem = wl & 7;
    unsigned e[8];

    auto process = [&](const unsigned* ev) {
#pragma unroll
        for (int k = 0; k < 8; ++k) {
            uint2 w = wst[ev[k] & 0x7fffu];
            x0 += __uint_as_float(w.x << 16);
            x1 += __uint_as_float(w.x & 0xffff0000u);
            x2 += __uint_as_float(w.y << 16);
            x3 += __uint_as_float(w.y & 0xffff0000u);
            if (ev[k] & 0x8000u) {
                float4 v;
                v.x = x0; v.y = x1; v.z = x2; v.w = x3;
                *(float4*)&dst[(size_t)(t + (kk << 9)) * L0] = v;
                ++kk; x0 = 0.f; x1 = 0.f; x2 = 0.f; x3 = 0.f;
            }
        }
    };

    if (nfull > 0) {
#pragma unroll
        for (int k = 0; k < 8; ++k) e[k] = estream[base + k * 64];
        base += 512;
        for (int it = 1; it < nfull; ++it) {
            unsigned f[8];
#pragma unroll
            for (int k = 0; k < 8; ++k) f[k] = estream[base + k * 64];
            base += 512;
            process(e);
#pragma unroll
            for (int k = 0; k < 8; ++k) e[k] = f[k];
        }
        process(e);
    }
    for (int k = 0; k < rem; ++k) {
        unsigned ev = estream[base + k * 64];
        uint2 w = wst[ev & 0x7fffu];
        x0 += __uint_as_float(w.x << 16);
        x1 += __uint_as_float(w.x & 0xffff0000u);
        x2 += __uint_as_float(w.y << 16);
        x3 += __uint_as_float(w.y & 0xffff0000u);
        if (ev & 0x8000u) {
            float4 v;
            v.x = x0; v.y = x1; v.z = x2; v.w = x3;
            *(float4*)&dst[(size_t)(t + (kk << 9)) * L0] = v;
            ++kk; x0 = 0.f; x1 = 0.f; x2 = 0.f; x3 = 0.f;
        }
    }
}

__global__ void cvtw1_kernel(const float* __restrict__ W1, __hip_bfloat16* __restrict__ W1b) {
    int i = blockIdx.x * 256 + threadIdx.x;  // one float4 each
    const int n = L1DIM * L0 / 4;
    if (i < n) {
        float4 v = ((const float4*)W1)[i];
        union { ushort4 u; __hip_bfloat16 h[4]; } pk;
        pk.h[0] = __float2bfloat16(v.x);
        pk.h[1] = __float2bfloat16(v.y);
        pk.h[2] = __float2bfloat16(v.z);
        pk.h[3] = __float2bfloat16(v.w);
        ((ushort4*)W1b)[i] = pk.u;
    }
}

// h1[b]      = relu(BASE[c] + SA[d1] + SB[d2])  (x1)
// h1[4096+b] = relu(BASE[c] + SA[d2] + SB[d1])  (x2)
__global__ __launch_bounds__(256) void build_h_kernel(const int* __restrict__ dp,
                                                      const int* __restrict__ cl,
                                                      const float* __restrict__ SA,
                                                      const float* __restrict__ SB,
                                                      const float* __restrict__ BASE,
                                                      __hip_bfloat16* __restrict__ h1) {
    int b = blockIdx.x;
    int d1 = dp[2 * b], d2 = dp[2 * b + 1], c = cl[b];
    const float* bs = BASE + (size_t)c * L0;
    const float* a1 = SA + (size_t)d1 * L0;
    const float* a2 = SA + (size_t)d2 * L0;
    const float* s1 = SB + (size_t)d1 * L0;
    const float* s2 = SB + (size_t)d2 * L0;
    for (int ch = threadIdx.x * 4; ch < L0; ch += 1024) {
        float4 vb = *(const float4*)(bs + ch);
        float4 va1 = *(const float4*)(a1 + ch);
        float4 va2 = *(const float4*)(a2 + ch);
        float4 vs1 = *(const float4*)(s1 + ch);
        float4 vs2 = *(const float4*)(s2 + ch);
        union { ushort4 u; __hip_bfloat16 h[4]; } p1, p2;
        const float* fb = (const float*)&vb;
        const float* fa1 = (const float*)&va1;
        const float* fa2 = (const float*)&va2;
        const float* fs1 = (const float*)&vs1;
        const float* fs2 = (const float*)&vs2;
#pragma unroll
        for (int j = 0; j < 4; ++j) {
            float z1 = fb[j] + fa1[j] + fs2[j];
            float z2 = fb[j] + fa2[j] + fs1[j];
            p1.h[j] = __float2bfloat16(fmaxf(z1, 0.f));
            p2.h[j] = __float2bfloat16(fmaxf(z2, 0.f));
        }
        *(ushort4*)((__hip_bfloat16*)h1 + (size_t)b * L0 + ch) = p1.u;
        *(ushort4*)((__hip_bfloat16*)h1 + (size_t)(BATCH + b) * L0 + ch) = p2.u;
    }
}

// C = relu(A @ B^T + bias), A: MxK bf16, B: NxK bf16 (W1), C: MxN bf16
#define BM 128
#define BN 128
#define BKK 32
__global__ __launch_bounds__(256) void gemm_kernel(const __hip_bfloat16* __restrict__ A,
                                                   const __hip_bfloat16* __restrict__ B,
                                                   const float* __restrict__ bias,
                                                   __hip_bfloat16* __restrict__ C,
                                                   int M, int N, int K) {
    __shared__ __hip_bfloat16 As[BM * BKK];
    __shared__ __hip_bfloat16 Bs[BN * BKK];
    int t = threadIdx.x;
    int ntiles = N / BN;
    int bx = blockIdx.x % ntiles;
    int by = blockIdx.x / ntiles;
    int brow = by * BM, bcol = bx * BN;
    int w = t >> 6, l = t & 63;
    int wr = w >> 1, wc = w & 1;
    f32x4 acc[4][4] = {};
    int row = l & 15, ko = (l >> 4) * 8;
    for (int k0 = 0; k0 < K; k0 += BKK) {
#pragma unroll
        for (int i = 0; i < 2; ++i) {
            int idx = i * 256 + t;
            int r = idx >> 2, cb = (idx & 3) * 8;
            __builtin_amdgcn_global_load_lds(
                (const __attribute__((address_space(1))) void*)(A + (size_t)(brow + r) * K + k0 + cb),
                (__attribute__((address_space(3))) void*)(&As[idx * 8]), 16, 0, 0);
            __builtin_amdgcn_global_load_lds(
                (const __attribute__((address_space(1))) void*)(B + (size_t)(bcol + r) * K + k0 + cb),
                (__attribute__((address_space(3))) void*)(&Bs[idx * 8]), 16, 0, 0);
        }
        __syncthreads();
        s16x8 af[4], bfr[4];
#pragma unroll
        for (int m = 0; m < 4; ++m)
            af[m] = *(const s16x8*)(&As[(wr * 64 + m * 16 + row) * BKK + ko]);
#pragma unroll
        for (int n = 0; n < 4; ++n)
            bfr[n] = *(const s16x8*)(&Bs[(wc * 64 + n * 16 + row) * BKK + ko]);
#pragma unroll
        for (int m = 0; m < 4; ++m)
#pragma unroll
            for (int n = 0; n < 4; ++n)
                acc[m][n] = __builtin_amdgcn_mfma_f32_16x16x32_bf16(af[m], bfr[n], acc[m][n], 0, 0, 0);
        __syncthreads();
    }
    int cr = (l >> 4) * 4;
    int cc = l & 15;
#pragma unroll
    for (int m = 0; m < 4; ++m)
#pragma unroll
        for (int n = 0; n < 4; ++n) {
#pragma unroll
            for (int j = 0; j < 4; ++j) {
                int grow = brow + wr * 64 + m * 16 + cr + j;
                int gcol = bcol + wc * 64 + n * 16 + cc;
                float v = acc[m][n][j] + bias[gcol];
                C[(size_t)grow * N + gcol] = __float2bfloat16(fmaxf(v, 0.f));
            }
        }
}

// out[r] = b2 + sum_o h2[r][o] * W2[o]
__global__ __launch_bounds__(128) void out_kernel(const __hip_bfloat16* __restrict__ h2,
                                                  const float* __restrict__ W2,
                                                  const float* __restrict__ b2,
                                                  float* __restrict__ out) {
    int r = blockIdx.x;
    int t = threadIdx.x;
    union { uint4 u; __hip_bfloat16 h[8]; } pk;
    pk.u = *(const uint4*)(h2 + (size_t)r * L1DIM + t * 8);
    float s = 0.f;
#pragma unroll
    for (int j = 0; j < 8; ++j) s += __bfloat162float(pk.h[j]) * W2[t * 8 + j];
    for (int o = 32; o > 0; o >>= 1) s += __shfl_down(s, o);
    __shared__ float red[2];
    if ((t & 63) == 0) red[t >> 6] = s;
    __syncthreads();
    if (t == 0) out[r] = red[0] + red[1] + b2[0];
}

extern "C" void kernel_launch(void* const* d_in, const int* in_sizes, int n_in,
                              void* d_out, int out_size, void* d_ws, size_t ws_size,
                              hipStream_t stream) {
    const int* drug_pairs = (const int*)d_in[0];
    const int* cell_lines = (const int*)d_in[1];
    const int* dpi_drug = (const int*)d_in[2];
    const int* dpi_prot = (const int*)d_in[3];
    const float* W0 = (const float*)d_in[4];
    const float* b0 = (const float*)d_in[5];
    const float* W1 = (const float*)d_in[6];
    const float* b1 = (const float*)d_in[7];
    const float* W2 = (const float*)d_in[8];
    const float* b2 = (const float*)d_in[9];
    float* out = (float*)d_out;

    char* ws = (char*)d_ws;
    size_t off = 0;
    auto alloc = [&](size_t bytes) {
        char* p = ws + off;
        off += (bytes + 255) & ~(size_t)255;
        return p;
    };
    float* SA = (float*)alloc((size_t)NDRUG * L0 * 4);
    float* SB = (float*)alloc((size_t)NDRUG * L0 * 4);
    float* BASE = (float*)alloc((size_t)NCELL * L0 * 4);
    __hip_bfloat16* W1b = (__hip_bfloat16*)alloc((size_t)L1DIM * L0 * 2);
    __hip_bfloat16* h1 = (__hip_bfloat16*)alloc((size_t)2 * BATCH * L0 * 2);
    __hip_bfloat16* h2 = (__hip_bfloat16*)alloc((size_t)2 * BATCH * L1DIM * 2);
    // contiguous zero region: hist, cnt
    const int ZREG_N = 2 * NDRUG;
    int* zreg = (int*)alloc((size_t)ZREG_N * 4);
    int* hist = zreg;
    int* cnt = zreg + NDRUG;
    int* dptr = (int*)alloc((size_t)(NDRUG + 1) * 4);
    int* dtmp = (int*)alloc((size_t)NEDGE * 4);
    int* dcnt = (int*)alloc((size_t)NDRUG * 4);
    int* wlen = (int*)alloc(8 * 4);
    int* wbase = (int*)alloc(8 * 4);
    int* pref = (int*)alloc((size_t)512 * 8 * 4);
    int* tcnt = (int*)alloc((size_t)512 * 4);
    unsigned short* estream = (unsigned short*)alloc((size_t)64 * (NEDGE + NDRUG + 512) * 2);

    zero_all_kernel<<<(ZREG_N + 255) / 256, 256, 0, stream>>>(zreg, ZREG_N);
    hist_kernel<<<(NEDGE + 255) / 256, 256, 0, stream>>>(dpi_drug, hist);
    scan_kernel<<<1, 256, 0, stream>>>(hist, dptr, NDRUG);
    scatter_kernel<<<(NEDGE + 255) / 256, 256, 0, stream>>>(dpi_drug, dpi_prot, dptr, cnt, dtmp);
    sortdedup_kernel<<<(NDRUG + 255) / 256, 256, 0, stream>>>(dptr, dtmp, dcnt);
    stream_meta_kernel<<<1, 512, 0, stream>>>(dcnt, wlen, wbase, pref, tcnt);
    fill_stream_kernel<<<(NDRUG + 512 + 255) / 256, 256, 0, stream>>>(dptr, dcnt, dtmp, wbase,
                                                                      wlen, pref, tcnt, estream);
    base_kernel<<<(NCELL * L0 + 255) / 256, 256, 0, stream>>>(W0, b0, BASE);
    drug_sum_kernel<<<L0 / 2, 512, 0, stream>>>(W0, estream, wbase, wlen, SA, SB);
    cvtw1_kernel<<<(L1DIM * L0 / 4 + 255) / 256, 256, 0, stream>>>(W1, W1b);
    build_h_kernel<<<BATCH, 256, 0, stream>>>(drug_pairs, cell_lines, SA, SB, BASE, h1);
    gemm_kernel<<<(2 * BATCH / BM) * (L1DIM / BN), 256, 0, stream>>>(h1, W1b, b1, h2,
                                                                     2 * BATCH, L1DIM, L0);
    out_kernel<<<2 * BATCH, 128, 0, stream>>>(h2, W2, b2, out);
}